// Round 1
// baseline (7052.798 us; speedup 1.0000x reference)
//
#include <hip/hip_runtime.h>

#define BATCH 32
#define NN0   20480

// ======================= CSR build =======================
__global__ __launch_bounds__(256) void count_kernel(const int* __restrict__ dst, int* __restrict__ cnt, int E) {
    int e = blockIdx.x * 256 + threadIdx.x;
    if (e < E) atomicAdd(&cnt[dst[e]], 1);
}

__global__ __launch_bounds__(256) void scan_kernel(const int* __restrict__ cnt, int* __restrict__ rowptr,
                                                   int* __restrict__ cursor, int n) {
    __shared__ int part[256];
    int tid = threadIdx.x;
    int per = (n + 255) / 256;
    int start = tid * per;
    int end = start + per; if (end > n) end = n; if (start > n) start = n;
    int s = 0;
    for (int i = start; i < end; ++i) s += cnt[i];
    part[tid] = s;
    __syncthreads();
    for (int off = 1; off < 256; off <<= 1) {
        int v = (tid >= off) ? part[tid - off] : 0;
        __syncthreads();
        part[tid] += v;
        __syncthreads();
    }
    int base = (tid == 0) ? 0 : part[tid - 1];
    for (int i = start; i < end; ++i) {
        rowptr[i] = base; cursor[i] = base;
        base += cnt[i];
    }
    if (tid == 255) rowptr[n] = base;
}

__global__ __launch_bounds__(256) void scatter_kernel(const int* __restrict__ src, const int* __restrict__ dst,
                                                      const float* __restrict__ nrm, int* __restrict__ cursor,
                                                      int* __restrict__ esrc, float* __restrict__ ewt,
                                                      int* __restrict__ eid, int E) {
    int e = blockIdx.x * 256 + threadIdx.x;
    if (e >= E) return;
    int p = atomicAdd(&cursor[dst[e]], 1);
    esrc[p] = src[e]; ewt[p] = nrm[e]; eid[p] = e;
}

__global__ __launch_bounds__(256) void sortrows_kernel(const int* __restrict__ rowptr, int* __restrict__ esrc,
                                                       float* __restrict__ ewt, int* __restrict__ eid, int N) {
    int m = blockIdx.x * 256 + threadIdx.x;
    if (m >= N) return;
    int a = rowptr[m], b = rowptr[m + 1];
    for (int i = a + 1; i < b; ++i) {
        int ke = eid[i]; int ks = esrc[i]; float kw = ewt[i];
        int j = i - 1;
        while (j >= a && eid[j] > ke) { eid[j+1]=eid[j]; esrc[j+1]=esrc[j]; ewt[j+1]=ewt[j]; --j; }
        eid[j+1] = ke; esrc[j+1] = ks; ewt[j+1] = kw;
    }
}

// ======================= dense prop GEMM: Z = s*(A·X) + t*Y (Z may alias Y) ===================
#define BM 64
#define BN 64
#define BKK 16
__global__ __launch_bounds__(256) void gemm_prop(const float* __restrict__ A, const float* __restrict__ X,
                                                 const float* __restrict__ Y, float* __restrict__ Z,
                                                 int M, int C, float s, float t) {
    __shared__ float As[BKK][BM + 4];
    __shared__ float Xs[BKK][BN + 4];
    const int bm = blockIdx.y * BM, bn = blockIdx.x * BN;
    const int tid = threadIdx.x;
    const int tx = tid & 15, ty = tid >> 4;
    float acc[4][4] = {};
    for (int k0 = 0; k0 < M; k0 += BKK) {
        {   // A tile 64x16, one float4 per thread
            int mm = tid >> 2;
            int kk = (tid & 3) * 4;
            const float4 v = *reinterpret_cast<const float4*>(&A[(size_t)(bm + mm) * M + k0 + kk]);
            As[kk + 0][mm] = v.x; As[kk + 1][mm] = v.y; As[kk + 2][mm] = v.z; As[kk + 3][mm] = v.w;
        }
        {   // X tile 16x64
            int kk = tid >> 4;
            int cc = (tid & 15) * 4;
            const float4 v = *reinterpret_cast<const float4*>(&X[(size_t)(k0 + kk) * C + bn + cc]);
            *reinterpret_cast<float4*>(&Xs[kk][cc]) = v;
        }
        __syncthreads();
#pragma unroll
        for (int kk = 0; kk < BKK; ++kk) {
            float a[4], xv[4];
            *reinterpret_cast<float4*>(a)  = *reinterpret_cast<const float4*>(&As[kk][ty * 4]);
            *reinterpret_cast<float4*>(xv) = *reinterpret_cast<const float4*>(&Xs[kk][tx * 4]);
#pragma unroll
            for (int i = 0; i < 4; ++i)
#pragma unroll
                for (int j = 0; j < 4; ++j) acc[i][j] += a[i] * xv[j];
        }
        __syncthreads();
    }
#pragma unroll
    for (int i = 0; i < 4; ++i) {
        const int m = bm + ty * 4 + i;
#pragma unroll
        for (int j = 0; j < 4; ++j) {
            const int c = bn + tx * 4 + j;
            float v = s * acc[i][j];
            if (t != 0.f) v += t * Y[(size_t)m * C + c];
            Z[(size_t)m * C + c] = v;
        }
    }
}

// ======================= epilogue: out (opt init w/ bias) += Tx·W_k, opt relu =================
// flags: 1=init, 2=relu.  FINAL -> out index = ((b*NN0+m)*FOUT+o)
template <int FIN, int FOUT, bool FINAL>
__global__ __launch_bounds__(256) void epilogue_k(const float* __restrict__ tx, const float* __restrict__ W,
                                                  const float* __restrict__ bias, float* __restrict__ out,
                                                  int M, int flags) {
    __shared__ float Ws[FIN * FOUT];
    int tid = threadIdx.x;
    for (int i = tid; i < FIN * FOUT; i += 256) Ws[i] = W[i];
    __syncthreads();
    int r = blockIdx.x * 256 + tid;
    if (r >= M * BATCH) return;
    const float* trow = tx + (size_t)r * FIN;
    float xin[FIN];
    if constexpr (FIN % 4 == 0) {
#pragma unroll
        for (int f4 = 0; f4 < FIN / 4; ++f4) {
            float4 v = reinterpret_cast<const float4*>(trow)[f4];
            xin[4*f4+0] = v.x; xin[4*f4+1] = v.y; xin[4*f4+2] = v.z; xin[4*f4+3] = v.w;
        }
    } else {
#pragma unroll
        for (int f = 0; f < FIN; ++f) xin[f] = trow[f];
    }
    float* orow;
    if constexpr (FINAL) {
        int m = r >> 5, b = r & 31;
        orow = out + ((size_t)b * NN0 + m) * FOUT;
    } else {
        orow = out + (size_t)r * FOUT;
    }
    const bool init = flags & 1, relu = flags & 2;
#pragma unroll
    for (int o = 0; o < FOUT; ++o) {
        float acc = 0.f;
#pragma unroll
        for (int f = 0; f < FIN; ++f) acc += xin[f] * Ws[f * FOUT + o];
        float val;
        if (init) { val = acc; if (bias) val += bias[o]; }
        else      { val = acc + orow[o]; }
        if (relu) val = fmaxf(val, 0.f);
        orow[o] = val;
    }
}

// ======================= sparse cheb step (CSR prop + fused W-accumulate) =====================
// txout[m,c] = s * sum_e w_e * txin[src_e, c] + t * txprev[m,c]  (txout may alias txprev)
// then out[m,b,:] += v[b,:]·W ; relu optional (applied to out)
template <int FIN, int FOUT, bool FINAL>
__global__ __launch_bounds__(256) void sparse_cheb_step(const int* __restrict__ rowptr, const int* __restrict__ esrc,
                                                        const float* __restrict__ ewt,
                                                        const float* __restrict__ txin, const float* __restrict__ txprev,
                                                        float* __restrict__ txout,
                                                        const float* __restrict__ W, float* __restrict__ out,
                                                        float s, float t, int relu) {
    constexpr int COLS = BATCH * FIN;
    constexpr int OC = BATCH * FOUT;
    __shared__ float vbuf[COLS];
    __shared__ float Ws[FIN * FOUT];
    const int m = blockIdx.x;
    const int tid = threadIdx.x;
    for (int i = tid; i < FIN * FOUT; i += 256) Ws[i] = W[i];
    const int e0 = rowptr[m], e1 = rowptr[m + 1];
    for (int c = tid; c < COLS; c += 256) {
        float acc = 0.f;
        for (int e = e0; e < e1; ++e)
            acc += ewt[e] * txin[(size_t)esrc[e] * COLS + c];
        float v = s * acc;
        if (t != 0.f) v += t * txprev[(size_t)m * COLS + c];
        txout[(size_t)m * COLS + c] = v;
        vbuf[c] = v;
    }
    __syncthreads();
    for (int i = tid; i < OC; i += 256) {
        int b = i / FOUT, o = i % FOUT;
        float acc = 0.f;
#pragma unroll
        for (int f = 0; f < FIN; ++f) acc += vbuf[b * FIN + f] * Ws[f * FOUT + o];
        size_t oidx;
        if constexpr (FINAL) oidx = ((size_t)b * NN0 + m) * FOUT + o;
        else                 oidx = ((size_t)m * BATCH + b) * FOUT + o;
        float val = out[oidx] + acc;
        if (relu) val = fmaxf(val, 0.f);
        out[oidx] = val;
    }
}

// ======================= pool, layout copy, FC =======================
__global__ __launch_bounds__(256) void pool_kernel(const int* __restrict__ idx, const float* __restrict__ w,
                                                   const float* __restrict__ in, float* __restrict__ out,
                                                   int M, int cols) {
    int g = blockIdx.x * 256 + threadIdx.x;
    if (g >= M * cols) return;
    int m = g / cols, c = g - m * cols;
    const int* ir = idx + m * 3; const float* wr = w + m * 3;
    float acc = wr[0] * in[(size_t)ir[0] * cols + c]
              + wr[1] * in[(size_t)ir[1] * cols + c]
              + wr[2] * in[(size_t)ir[2] * cols + c];
    out[g] = acc;
}

__global__ __launch_bounds__(256) void xcopy_kernel(const float* __restrict__ x, float* __restrict__ o, int N, int F) {
    int g = blockIdx.x * 256 + threadIdx.x;
    if (g >= N * BATCH * F) return;
    int f = g % F; int nb = g / F; int b = nb % BATCH; int n = nb / BATCH;
    o[g] = x[((size_t)b * N + n) * F + f];
}

__global__ __launch_bounds__(64) void fc_enc_kernel(const float* __restrict__ h, const float* __restrict__ w,
                                                    const float* __restrict__ bias, float* __restrict__ z) {
    int b = blockIdx.x; int o = threadIdx.x;   // 32 blocks x 64 threads
    float acc = bias[o];
    for (int n = 0; n < 80; ++n)
#pragma unroll
        for (int f = 0; f < 32; ++f)
            acc += h[((size_t)n * 32 + b) * 32 + f] * w[(size_t)o * 2560 + n * 32 + f];
    z[b * 64 + o] = fmaxf(acc, 0.f);
}

__global__ __launch_bounds__(256) void fc_dec_kernel(const float* __restrict__ z, const float* __restrict__ w,
                                                     const float* __restrict__ bias, float* __restrict__ out) {
    int g = blockIdx.x * 256 + threadIdx.x;   // 80*32*32 = 81920, layout [n][b][f]
    if (g >= 80 * 32 * 32) return;
    int f = g % 32; int b = (g / 32) % 32; int n = g / 1024;
    int j = n * 32 + f;
    float acc = bias[j];
    const float* wr = w + (size_t)j * 64;
    const float* zr = z + b * 64;
#pragma unroll
    for (int o = 0; o < 64; ++o) acc += zr[o] * wr[o];
    out[g] = fmaxf(acc, 0.f);
}

// ======================= host orchestration =======================
extern "C" void kernel_launch(void* const* d_in, const int* in_sizes, int n_in,
                              void* d_out, int out_size, void* d_ws, size_t ws_size,
                              hipStream_t stream) {
    (void)n_in; (void)out_size; (void)ws_size;
    const float* x     = (const float*)d_in[0];
    const int*   ei    = (const int*)d_in[1];
    const float* anorm = (const float*)d_in[2];
    const float* adjs[3] = { (const float*)d_in[4], (const float*)d_in[5], (const float*)d_in[6] };
    const int*   dn_idx[4] = { (const int*)d_in[7],  (const int*)d_in[11], (const int*)d_in[15], (const int*)d_in[19] };
    const float* dn_w[4]   = { (const float*)d_in[8],(const float*)d_in[12],(const float*)d_in[16],(const float*)d_in[20] };
    const int*   up_idx[4] = { (const int*)d_in[9],  (const int*)d_in[13], (const int*)d_in[17], (const int*)d_in[21] };
    const float* up_w[4]   = { (const float*)d_in[10],(const float*)d_in[14],(const float*)d_in[18],(const float*)d_in[22] };
    const float* W_enc[4] = { (const float*)d_in[23], (const float*)d_in[25], (const float*)d_in[27], (const float*)d_in[29] };
    const float* b_enc[4] = { (const float*)d_in[24], (const float*)d_in[26], (const float*)d_in[28], (const float*)d_in[30] };
    const float* W_dec[5] = { (const float*)d_in[31], (const float*)d_in[33], (const float*)d_in[35], (const float*)d_in[37], (const float*)d_in[39] };
    const float* b_dec[4] = { (const float*)d_in[32], (const float*)d_in[34], (const float*)d_in[36], (const float*)d_in[38] };
    const float* enc_w = (const float*)d_in[40];
    const float* enc_b = (const float*)d_in[41];
    const float* dec_w = (const float*)d_in[42];
    const float* dec_b = (const float*)d_in[43];
    const int E = in_sizes[2];

    // ---- workspace carve: 3 big ping-pong buffers + CSR (~127.5 MB total) ----
    const size_t SZ0 = (size_t)NN0 * BATCH * 16;   // 10,485,760 floats
    float* bigA = (float*)d_ws;
    float* bigB = bigA + SZ0;
    float* bigC = bigB + SZ0;
    char* p = (char*)(bigC + SZ0);
    int* rowptr = (int*)p;  p += (NN0 + 1) * sizeof(int);
    int* cnt    = (int*)p;  p += NN0 * sizeof(int);
    int* cursor = (int*)p;  p += NN0 * sizeof(int);
    int* esrc   = (int*)p;  p += (size_t)E * sizeof(int);
    int* eid    = (int*)p;  p += (size_t)E * sizeof(int);
    float* ewt  = (float*)p;
    // small buffers nested inside bigB (dead regions at their time of use)
    float* txS0 = bigB;                 // 20480*32*3 floats
    float* txS1 = bigB + SZ0 / 2;
    float* lat0 = bigB;                 // 80*32*32
    float* zb   = bigB + 200000;        // 32*64
    float* lat1 = bigB + 300000;        // 80*32*32

    // ---- CSR build (deterministic via per-row sort by edge id) ----
    hipMemsetAsync(cnt, 0, NN0 * sizeof(int), stream);
    count_kernel<<<(E + 255) / 256, 256, 0, stream>>>(ei + E, cnt, E);
    scan_kernel<<<1, 256, 0, stream>>>(cnt, rowptr, cursor, NN0);
    scatter_kernel<<<(E + 255) / 256, 256, 0, stream>>>(ei, ei + E, anorm, cursor, esrc, ewt, eid, E);
    sortrows_kernel<<<(NN0 + 255) / 256, 256, 0, stream>>>(rowptr, esrc, ewt, eid, NN0);

    // ---- dispatch helpers ----
    auto epi = [&](int FIN, int FOUT, bool FINAL, const float* tx, const float* W, const float* bias,
                   float* out, int M, int flags) {
        int blocks = (M * BATCH + 255) / 256;
        if (FINAL)                        epilogue_k<16, 3, true ><<<blocks, 256, 0, stream>>>(tx, W, bias, out, M, flags);
        else if (FIN == 3)                epilogue_k<3, 16, false><<<blocks, 256, 0, stream>>>(tx, W, bias, out, M, flags);
        else if (FIN == 16 && FOUT == 16) epilogue_k<16, 16, false><<<blocks, 256, 0, stream>>>(tx, W, bias, out, M, flags);
        else if (FIN == 16 && FOUT == 32) epilogue_k<16, 32, false><<<blocks, 256, 0, stream>>>(tx, W, bias, out, M, flags);
        else                              epilogue_k<32, 16, false><<<blocks, 256, 0, stream>>>(tx, W, bias, out, M, flags);
    };
    auto sparse_step = [&](int FIN, bool FINAL, const float* txin, const float* txprev, float* txout,
                           const float* W, float* out, float s, float t, int relu) {
        if (FINAL)        sparse_cheb_step<16, 3, true ><<<NN0, 256, 0, stream>>>(rowptr, esrc, ewt, txin, txprev, txout, W, out, s, t, relu);
        else if (FIN == 3) sparse_cheb_step<3, 16, false><<<NN0, 256, 0, stream>>>(rowptr, esrc, ewt, txin, txprev, txout, W, out, s, t, relu);
        else               sparse_cheb_step<16, 16, false><<<NN0, 256, 0, stream>>>(rowptr, esrc, ewt, txin, txprev, txout, W, out, s, t, relu);
    };
    auto gemm = [&](const float* A, const float* X, const float* Y, float* Z, int M, int C, float s, float t) {
        dim3 grid(C / BN, M / BM);
        gemm_prop<<<grid, 256, 0, stream>>>(A, X, Y, Z, M, C, s, t);
    };
    auto cheb_dense = [&](const float* A, int M, int FIN, int FOUT, const float* W, const float* bias,
                          float* h, float* tmp, float* out, bool relu) {
        const int C = BATCH * FIN;
        epi(FIN, FOUT, false, h, W, bias, out, M, 1);
        gemm(A, h, nullptr, tmp, M, C, 1.f, 0.f);
        epi(FIN, FOUT, false, tmp, W + 1 * FIN * FOUT, nullptr, out, M, 0);
        float* prev = h; float* cur = tmp;
        for (int k = 2; k < 6; ++k) {
            gemm(A, cur, prev, prev, M, C, 2.f, -1.f);
            epi(FIN, FOUT, false, prev, W + k * FIN * FOUT, nullptr, out, M, (k == 5 && relu) ? 2 : 0);
            float* t2 = prev; prev = cur; cur = t2;
        }
    };
    auto cheb_sparse = [&](int FIN, int FOUT, bool FINAL, const float* W, const float* bias,
                           float* h, float* tmp, float* out, bool relu) {
        epi(FIN, FOUT, FINAL, h, W, bias, out, NN0, 1);
        sparse_step(FIN, FINAL, h, nullptr, tmp, W + 1 * FIN * FOUT, out, 1.f, 0.f, 0);
        float* prev = h; float* cur = tmp;
        for (int k = 2; k < 6; ++k) {
            sparse_step(FIN, FINAL, cur, prev, prev, W + k * FIN * FOUT, out, 2.f, -1.f, (k == 5 && relu) ? 1 : 0);
            float* t2 = prev; prev = cur; cur = t2;
        }
    };
    auto pool = [&](const int* idx, const float* w, int M, int cols, const float* in, float* out) {
        pool_kernel<<<((size_t)M * cols + 255) / 256, 256, 0, stream>>>(idx, w, in, out, M, cols);
    };

    // ======================= network =======================
    // encoder
    xcopy_kernel<<<(NN0 * BATCH * 3 + 255) / 256, 256, 0, stream>>>(x, txS0, NN0, 3);
    cheb_sparse(3, 16, false, W_enc[0], b_enc[0], txS0, txS1, bigA, true);
    pool(dn_idx[0], dn_w[0], 5120, 512, bigA, bigB);
    cheb_dense(adjs[0], 5120, 16, 16, W_enc[1], b_enc[1], bigB, bigC, bigA, true);
    pool(dn_idx[1], dn_w[1], 1280, 512, bigA, bigB);
    cheb_dense(adjs[1], 1280, 16, 16, W_enc[2], b_enc[2], bigB, bigC, bigA, true);
    pool(dn_idx[2], dn_w[2], 320, 512, bigA, bigB);
    cheb_dense(adjs[2], 320, 16, 32, W_enc[3], b_enc[3], bigB, bigC, bigA, true);
    pool(dn_idx[3], dn_w[3], 80, 1024, bigA, lat0);
    fc_enc_kernel<<<32, 64, 0, stream>>>(lat0, enc_w, enc_b, zb);
    // decoder
    fc_dec_kernel<<<(80 * 32 * 32 + 255) / 256, 256, 0, stream>>>(zb, dec_w, dec_b, lat1);
    pool(up_idx[3], up_w[3], 320, 1024, lat1, bigA);
    cheb_dense(adjs[2], 320, 32, 16, W_dec[0], b_dec[0], bigA, bigB, bigC, true);
    pool(up_idx[2], up_w[2], 1280, 512, bigC, bigA);
    cheb_dense(adjs[1], 1280, 16, 16, W_dec[1], b_dec[1], bigA, bigB, bigC, true);
    pool(up_idx[1], up_w[1], 5120, 512, bigC, bigA);
    cheb_dense(adjs[0], 5120, 16, 16, W_dec[2], b_dec[2], bigA, bigB, bigC, true);
    pool(up_idx[0], up_w[0], NN0, 512, bigC, bigA);
    cheb_sparse(16, 16, false, W_dec[3], b_dec[3], bigA, bigB, bigC, true);
    cheb_sparse(16, 3, true, W_dec[4], nullptr, bigC, bigA, (float*)d_out, false);
}

// Round 2
// 2570.950 us; speedup vs baseline: 2.7433x; 2.7433x over previous
//
#include <hip/hip_runtime.h>

#define BATCH 32
#define NN0   20480

typedef __attribute__((ext_vector_type(8))) short short8v;
typedef __attribute__((ext_vector_type(4))) float f32x4;

__device__ __forceinline__ float bf2f(unsigned short h) {
    return __uint_as_float(((unsigned int)h) << 16);
}
__device__ __forceinline__ unsigned short f2bf(float x) {
    unsigned int u = __float_as_uint(x);
    u += 0x7fff + ((u >> 16) & 1);   // RNE
    return (unsigned short)(u >> 16);
}

// ======================= CSR build =======================
__global__ __launch_bounds__(256) void count_kernel(const int* __restrict__ dst, int* __restrict__ cnt, int E) {
    int e = blockIdx.x * 256 + threadIdx.x;
    if (e < E) atomicAdd(&cnt[dst[e]], 1);
}

__global__ __launch_bounds__(256) void scan_kernel(const int* __restrict__ cnt, int* __restrict__ rowptr,
                                                   int* __restrict__ cursor, int n) {
    __shared__ int part[256];
    int tid = threadIdx.x;
    int per = (n + 255) / 256;
    int start = tid * per;
    int end = start + per; if (end > n) end = n; if (start > n) start = n;
    int s = 0;
    for (int i = start; i < end; ++i) s += cnt[i];
    part[tid] = s;
    __syncthreads();
    for (int off = 1; off < 256; off <<= 1) {
        int v = (tid >= off) ? part[tid - off] : 0;
        __syncthreads();
        part[tid] += v;
        __syncthreads();
    }
    int base = (tid == 0) ? 0 : part[tid - 1];
    for (int i = start; i < end; ++i) {
        rowptr[i] = base; cursor[i] = base;
        base += cnt[i];
    }
    if (tid == 255) rowptr[n] = base;
}

__global__ __launch_bounds__(256) void scatter_kernel(const int* __restrict__ src, const int* __restrict__ dst,
                                                      const float* __restrict__ nrm, int* __restrict__ cursor,
                                                      int* __restrict__ esrc, float* __restrict__ ewt,
                                                      int* __restrict__ eid, int E) {
    int e = blockIdx.x * 256 + threadIdx.x;
    if (e >= E) return;
    int p = atomicAdd(&cursor[dst[e]], 1);
    esrc[p] = src[e]; ewt[p] = nrm[e]; eid[p] = e;
}

__global__ __launch_bounds__(256) void sortrows_kernel(const int* __restrict__ rowptr, int* __restrict__ esrc,
                                                       float* __restrict__ ewt, int* __restrict__ eid, int N) {
    int m = blockIdx.x * 256 + threadIdx.x;
    if (m >= N) return;
    int a = rowptr[m], b = rowptr[m + 1];
    for (int i = a + 1; i < b; ++i) {
        int ke = eid[i]; int ks = esrc[i]; float kw = ewt[i];
        int j = i - 1;
        while (j >= a && eid[j] > ke) { eid[j+1]=eid[j]; esrc[j+1]=esrc[j]; ewt[j+1]=ewt[j]; --j; }
        eid[j+1] = ke; esrc[j+1] = ks; ewt[j+1] = kw;
    }
}

// ======================= converts =======================
__global__ __launch_bounds__(256) void convert_flat(const float* __restrict__ in, unsigned short* __restrict__ out,
                                                    size_t n4) {
    // n4 = n/4
    for (size_t i = blockIdx.x * 256 + threadIdx.x; i < n4; i += (size_t)gridDim.x * 256) {
        float4 v = reinterpret_cast<const float4*>(in)[i];
        ushort4 o;
        o.x = f2bf(v.x); o.y = f2bf(v.y); o.z = f2bf(v.z); o.w = f2bf(v.w);
        reinterpret_cast<ushort4*>(out)[i] = o;
    }
}

// fp32 [M][C] -> bf16 [C][M]
__global__ __launch_bounds__(256) void convert_T(const float* __restrict__ in, unsigned short* __restrict__ out,
                                                 int M, int C) {
    __shared__ float tile[32][33];
    int m0 = blockIdx.x * 32, c0 = blockIdx.y * 32;
    int tx = threadIdx.x & 31, ty = threadIdx.x >> 5;   // 32 x 8
#pragma unroll
    for (int i = 0; i < 4; ++i) {
        int m = m0 + ty + i * 8;
        tile[ty + i * 8][tx] = in[(size_t)m * C + c0 + tx];
    }
    __syncthreads();
#pragma unroll
    for (int i = 0; i < 4; ++i) {
        int c = c0 + ty + i * 8;
        out[(size_t)c * M + m0 + tx] = f2bf(tile[tx][ty + i * 8]);
    }
}

// ======================= MFMA prop GEMM ==========================
// P[m][c] = sum_k A[m][k] * X[c][k];  T_out[c][m] = bf16( s*P + t*Prev[c][m] )
// A bf16 [M][K] (K==M), X bf16 [C][K], Prev/Out bf16 [C][M].
// Block: 256 thr (4 waves), tile BM=MF*64 (m) x 64 (c). BK=64. XOR-swizzled LDS.
template <int MF>
__global__ __launch_bounds__(256) void gemm_mfma(const unsigned short* __restrict__ Ab,
                                                 const unsigned short* __restrict__ Xb,
                                                 const unsigned short* __restrict__ Pb,
                                                 unsigned short* __restrict__ Ob,
                                                 int Mn, float s, float t) {
    constexpr int BM = MF * 64;
    const int K = Mn;
    __shared__ unsigned short As[BM * 64];
    __shared__ unsigned short Xs[64 * 64];
    const int tid = threadIdx.x;
    const int lane = tid & 63, wid = tid >> 6;
    const int bm = blockIdx.y * BM, bc = blockIdx.x * 64;

    f32x4 acc[MF][4] = {};
    constexpr int SEGA = (BM * 64 * 2) / 1024 / 4;   // A 1KB-segments per wave (MF=2 -> 4, MF=1 -> 2)

    for (int k0 = 0; k0 < K; k0 += 64) {
        __syncthreads();
        // stage A tile [BM][64] bf16, linear LDS, source pre-swizzled (st-16x32 style)
#pragma unroll
        for (int i = 0; i < SEGA; ++i) {
            int o = (wid * SEGA + i) * 1024 + lane * 16;
            int row = o >> 7;
            int colb = (o & 127) ^ ((row & 7) << 4);
            const unsigned short* g = Ab + (size_t)(bm + row) * K + k0 + (colb >> 1);
            __builtin_amdgcn_global_load_lds((const __attribute__((address_space(1))) void*)g,
                                             (__attribute__((address_space(3))) void*)((char*)As + (size_t)(wid * SEGA + i) * 1024),
                                             16, 0, 0);
        }
        // stage X tile [64][64]
#pragma unroll
        for (int i = 0; i < 2; ++i) {
            int o = (wid * 2 + i) * 1024 + lane * 16;
            int row = o >> 7;
            int colb = (o & 127) ^ ((row & 7) << 4);
            const unsigned short* g = Xb + (size_t)(bc + row) * K + k0 + (colb >> 1);
            __builtin_amdgcn_global_load_lds((const __attribute__((address_space(1))) void*)g,
                                             (__attribute__((address_space(3))) void*)((char*)Xs + (size_t)(wid * 2 + i) * 1024),
                                             16, 0, 0);
        }
        __syncthreads();
#pragma unroll
        for (int kk = 0; kk < 2; ++kk) {
            short8v a[MF], b[4];
#pragma unroll
            for (int mf = 0; mf < MF; ++mf) {
                int r = wid * (MF * 16) + mf * 16 + (lane & 15);
                int cb = kk * 64 + ((lane >> 4) * 16);
                int addr = r * 128 + (cb ^ ((r & 7) << 4));
                a[mf] = *reinterpret_cast<const short8v*>((const char*)As + addr);
            }
#pragma unroll
            for (int cf = 0; cf < 4; ++cf) {
                int r = cf * 16 + (lane & 15);
                int cb = kk * 64 + ((lane >> 4) * 16);
                int addr = r * 128 + (cb ^ ((r & 7) << 4));
                b[cf] = *reinterpret_cast<const short8v*>((const char*)Xs + addr);
            }
#pragma unroll
            for (int mf = 0; mf < MF; ++mf)
#pragma unroll
                for (int cf = 0; cf < 4; ++cf)
                    acc[mf][cf] = __builtin_amdgcn_mfma_f32_16x16x32_bf16(a[mf], b[cf], acc[mf][cf], 0, 0, 0);
        }
    }

    // epilogue: per frag, lane holds col c fixed, rows m0..m0+3 -> 8B packed stores to [C][M]
#pragma unroll
    for (int mf = 0; mf < MF; ++mf) {
        int m0 = bm + wid * (MF * 16) + mf * 16 + ((lane >> 4) * 4);
#pragma unroll
        for (int cf = 0; cf < 4; ++cf) {
            int c = bc + cf * 16 + (lane & 15);
            size_t base = (size_t)c * Mn + m0;
            float v0 = s * acc[mf][cf][0], v1 = s * acc[mf][cf][1];
            float v2 = s * acc[mf][cf][2], v3 = s * acc[mf][cf][3];
            if (Pb) {
                uint2 pv = *reinterpret_cast<const uint2*>(Pb + base);
                v0 += t * bf2f((unsigned short)(pv.x & 0xffff));
                v1 += t * bf2f((unsigned short)(pv.x >> 16));
                v2 += t * bf2f((unsigned short)(pv.y & 0xffff));
                v3 += t * bf2f((unsigned short)(pv.y >> 16));
            }
            uint2 ov;
            ov.x = (unsigned int)f2bf(v0) | ((unsigned int)f2bf(v1) << 16);
            ov.y = (unsigned int)f2bf(v2) | ((unsigned int)f2bf(v3) << 16);
            *reinterpret_cast<uint2*>(Ob + base) = ov;
        }
    }
}

// ======================= fused layer epilogue =========================
// out[m][b*FOUT+o] = relu?( bias[o] + sum_k sum_f T_k[b*FIN+f][m] * W[k][f][o] )
template <int FIN, int FOUT>
__global__ __launch_bounds__(256) void epi_layer(const unsigned short* __restrict__ Tb, size_t tslot,
                                                 const float* __restrict__ W, const float* __restrict__ bias,
                                                 float* __restrict__ out, int M, int relu) {
    __shared__ float Ws[6 * FIN * FOUT];
    for (int i = threadIdx.x; i < 6 * FIN * FOUT; i += 256) Ws[i] = W[i];
    __syncthreads();
    int g = blockIdx.x * 256 + threadIdx.x;   // g = b*M + m
    int b = g / M, m = g - b * M;
    float o_acc[FOUT];
#pragma unroll
    for (int o = 0; o < FOUT; ++o) o_acc[o] = bias ? bias[o] : 0.f;
    for (int k = 0; k < 6; ++k) {
        const unsigned short* Tk = Tb + (size_t)k * tslot + (size_t)b * FIN * M + m;
#pragma unroll
        for (int f = 0; f < FIN; ++f) {
            float xf = bf2f(Tk[(size_t)f * M]);
#pragma unroll
            for (int o = 0; o < FOUT; ++o) o_acc[o] += xf * Ws[(k * FIN + f) * FOUT + o];
        }
    }
    float* orow = out + (size_t)m * (32 * FOUT) + b * FOUT;
#pragma unroll
    for (int o = 0; o < FOUT; ++o) {
        float v = o_acc[o];
        if (relu) v = fmaxf(v, 0.f);
        orow[o] = v;
    }
}

// ======================= epilogue (sparse init): out = h*W0 (+bias) =================
template <int FIN, int FOUT, bool FINAL>
__global__ __launch_bounds__(256) void epilogue_k(const float* __restrict__ tx, const float* __restrict__ W,
                                                  const float* __restrict__ bias, float* __restrict__ out,
                                                  int M, int flags) {
    __shared__ float Ws[FIN * FOUT];
    int tid = threadIdx.x;
    for (int i = tid; i < FIN * FOUT; i += 256) Ws[i] = W[i];
    __syncthreads();
    int r = blockIdx.x * 256 + tid;
    if (r >= M * BATCH) return;
    const float* trow = tx + (size_t)r * FIN;
    float xin[FIN];
#pragma unroll
    for (int f = 0; f < FIN; ++f) xin[f] = trow[f];
    float* orow;
    if constexpr (FINAL) {
        int m = r >> 5, b = r & 31;
        orow = out + ((size_t)b * NN0 + m) * FOUT;
    } else {
        orow = out + (size_t)r * FOUT;
    }
    const bool init = flags & 1, relu = flags & 2;
#pragma unroll
    for (int o = 0; o < FOUT; ++o) {
        float acc = 0.f;
#pragma unroll
        for (int f = 0; f < FIN; ++f) acc += xin[f] * Ws[f * FOUT + o];
        float val;
        if (init) { val = acc; if (bias) val += bias[o]; }
        else      { val = acc + orow[o]; }
        if (relu) val = fmaxf(val, 0.f);
        orow[o] = val;
    }
}

// ======================= sparse cheb step =====================
template <int FIN, int FOUT, bool FINAL>
__global__ __launch_bounds__(256) void sparse_cheb_step(const int* __restrict__ rowptr, const int* __restrict__ esrc,
                                                        const float* __restrict__ ewt,
                                                        const float* __restrict__ txin, const float* __restrict__ txprev,
                                                        float* __restrict__ txout,
                                                        const float* __restrict__ W, float* __restrict__ out,
                                                        float s, float t, int relu) {
    constexpr int COLS = BATCH * FIN;
    constexpr int OC = BATCH * FOUT;
    constexpr int CPT = (COLS + 255) / 256;
    __shared__ float vbuf[COLS];
    __shared__ float Ws[FIN * FOUT];
    const int m = blockIdx.x;
    const int tid = threadIdx.x;
    for (int i = tid; i < FIN * FOUT; i += 256) Ws[i] = W[i];
    const int e0 = rowptr[m], e1 = rowptr[m + 1];
    float acc[CPT];
#pragma unroll
    for (int j = 0; j < CPT; ++j) acc[j] = 0.f;
    for (int e = e0; e < e1; ++e) {
        float w = ewt[e];
        const float* r = txin + (size_t)esrc[e] * COLS;
#pragma unroll
        for (int j = 0; j < CPT; ++j) {
            int c = tid + j * 256;
            if (c < COLS) acc[j] += w * r[c];
        }
    }
#pragma unroll
    for (int j = 0; j < CPT; ++j) {
        int c = tid + j * 256;
        if (c < COLS) {
            float v = s * acc[j];
            if (t != 0.f) v += t * txprev[(size_t)m * COLS + c];
            txout[(size_t)m * COLS + c] = v;
            vbuf[c] = v;
        }
    }
    __syncthreads();
    for (int i = tid; i < OC; i += 256) {
        int b = i / FOUT, o = i % FOUT;
        float acc2 = 0.f;
#pragma unroll
        for (int f = 0; f < FIN; ++f) acc2 += vbuf[b * FIN + f] * Ws[f * FOUT + o];
        size_t oidx;
        if constexpr (FINAL) oidx = ((size_t)b * NN0 + m) * FOUT + o;
        else                 oidx = ((size_t)m * BATCH + b) * FOUT + o;
        float val = out[oidx] + acc2;
        if (relu) val = fmaxf(val, 0.f);
        out[oidx] = val;
    }
}

// ======================= pool, layout copy, FC =======================
__global__ __launch_bounds__(256) void pool_kernel(const int* __restrict__ idx, const float* __restrict__ w,
                                                   const float* __restrict__ in, float* __restrict__ out,
                                                   int M, int cols) {
    int g = blockIdx.x * 256 + threadIdx.x;
    if (g >= M * cols) return;
    int m = g / cols, c = g - m * cols;
    const int* ir = idx + m * 3; const float* wr = w + m * 3;
    float acc = wr[0] * in[(size_t)ir[0] * cols + c]
              + wr[1] * in[(size_t)ir[1] * cols + c]
              + wr[2] * in[(size_t)ir[2] * cols + c];
    out[g] = acc;
}

__global__ __launch_bounds__(256) void xcopy_kernel(const float* __restrict__ x, float* __restrict__ o, int N, int F) {
    int g = blockIdx.x * 256 + threadIdx.x;
    if (g >= N * BATCH * F) return;
    int f = g % F; int nb = g / F; int b = nb % BATCH; int n = nb / BATCH;
    o[g] = x[((size_t)b * N + n) * F + f];
}

__global__ __launch_bounds__(64) void fc_enc_kernel(const float* __restrict__ h, const float* __restrict__ w,
                                                    const float* __restrict__ bias, float* __restrict__ z) {
    int b = blockIdx.x; int o = threadIdx.x;
    float acc = bias[o];
    for (int n = 0; n < 80; ++n)
#pragma unroll
        for (int f = 0; f < 32; ++f)
            acc += h[((size_t)n * 32 + b) * 32 + f] * w[(size_t)o * 2560 + n * 32 + f];
    z[b * 64 + o] = fmaxf(acc, 0.f);
}

__global__ __launch_bounds__(256) void fc_dec_kernel(const float* __restrict__ z, const float* __restrict__ w,
                                                     const float* __restrict__ bias, float* __restrict__ out) {
    int g = blockIdx.x * 256 + threadIdx.x;
    if (g >= 80 * 32 * 32) return;
    int f = g % 32; int b = (g / 32) % 32; int n = g / 1024;
    int j = n * 32 + f;
    float acc = bias[j];
    const float* wr = w + (size_t)j * 64;
    const float* zr = z + b * 64;
#pragma unroll
    for (int o = 0; o < 64; ++o) acc += zr[o] * wr[o];
    out[g] = fmaxf(acc, 0.f);
}

// ======================= host orchestration =======================
extern "C" void kernel_launch(void* const* d_in, const int* in_sizes, int n_in,
                              void* d_out, int out_size, void* d_ws, size_t ws_size,
                              hipStream_t stream) {
    (void)n_in; (void)out_size; (void)ws_size;
    const float* x     = (const float*)d_in[0];
    const int*   ei    = (const int*)d_in[1];
    const float* anorm = (const float*)d_in[2];
    const float* adjs[3] = { (const float*)d_in[4], (const float*)d_in[5], (const float*)d_in[6] };
    const int*   dn_idx[4] = { (const int*)d_in[7],  (const int*)d_in[11], (const int*)d_in[15], (const int*)d_in[19] };
    const float* dn_w[4]   = { (const float*)d_in[8],(const float*)d_in[12],(const float*)d_in[16],(const float*)d_in[20] };
    const int*   up_idx[4] = { (const int*)d_in[9],  (const int*)d_in[13], (const int*)d_in[17], (const int*)d_in[21] };
    const float* up_w[4]   = { (const float*)d_in[10],(const float*)d_in[14],(const float*)d_in[18],(const float*)d_in[22] };
    const float* W_enc[4] = { (const float*)d_in[23], (const float*)d_in[25], (const float*)d_in[27], (const float*)d_in[29] };
    const float* b_enc[4] = { (const float*)d_in[24], (const float*)d_in[26], (const float*)d_in[28], (const float*)d_in[30] };
    const float* W_dec[5] = { (const float*)d_in[31], (const float*)d_in[33], (const float*)d_in[35], (const float*)d_in[37], (const float*)d_in[39] };
    const float* b_dec[4] = { (const float*)d_in[32], (const float*)d_in[34], (const float*)d_in[36], (const float*)d_in[38] };
    const float* enc_w = (const float*)d_in[40];
    const float* enc_b = (const float*)d_in[41];
    const float* dec_w = (const float*)d_in[42];
    const float* dec_b = (const float*)d_in[43];
    const int E = in_sizes[2];

    // ---- workspace carve ----
    const size_t SZ0 = (size_t)NN0 * BATCH * 16;   // 10,485,760 floats (42 MB)
    float* bigA = (float*)d_ws;
    float* bigB = bigA + SZ0;
    float* bigC = bigB + SZ0;
    unsigned short* Tb = (unsigned short*)bigC;    // 6 bf16 shadow slots live inside bigC during dense levels
    char* p = (char*)(bigC + SZ0);
    unsigned short* adj1b = (unsigned short*)p; p += (size_t)5120 * 5120 * 2;
    unsigned short* adj2b = (unsigned short*)p; p += (size_t)1280 * 1280 * 2;
    unsigned short* adj3b = (unsigned short*)p; p += (size_t)320 * 320 * 2;
    int* rowptr = (int*)p;  p += (NN0 + 1) * sizeof(int);
    int* cnt    = (int*)p;  p += NN0 * sizeof(int);
    int* cursor = (int*)p;  p += NN0 * sizeof(int);
    int* esrc   = (int*)p;  p += (size_t)E * sizeof(int);
    int* eid    = (int*)p;  p += (size_t)E * sizeof(int);
    float* ewt  = (float*)p;
    float* txS0 = bigB;
    float* txS1 = bigB + SZ0 / 2;
    float* lat0 = bigB;
    float* zb   = bigB + 200000;
    float* lat1 = bigB + 300000;

    // ---- CSR build ----
    hipMemsetAsync(cnt, 0, NN0 * sizeof(int), stream);
    count_kernel<<<(E + 255) / 256, 256, 0, stream>>>(ei + E, cnt, E);
    scan_kernel<<<1, 256, 0, stream>>>(cnt, rowptr, cursor, NN0);
    scatter_kernel<<<(E + 255) / 256, 256, 0, stream>>>(ei, ei + E, anorm, cursor, esrc, ewt, eid, E);
    sortrows_kernel<<<(NN0 + 255) / 256, 256, 0, stream>>>(rowptr, esrc, ewt, eid, NN0);

    // ---- adjacency bf16 conversion (per launch) ----
    convert_flat<<<2048, 256, 0, stream>>>(adjs[0], adj1b, (size_t)5120 * 5120 / 4);
    convert_flat<<<512, 256, 0, stream>>>(adjs[1], adj2b, (size_t)1280 * 1280 / 4);
    convert_flat<<<64, 256, 0, stream>>>(adjs[2], adj3b, (size_t)320 * 320 / 4);

    // ---- dense cheb layer via MFMA ----
    auto cheb_mfma = [&](const unsigned short* Ab, int M, int FIN, int FOUT,
                         const float* W, const float* bias, const float* h, float* out, bool relu) {
        const int C = 32 * FIN;
        const size_t tslot = (size_t)C * M;
        dim3 cg(M / 32, C / 32);
        convert_T<<<cg, 256, 0, stream>>>(h, Tb, M, C);
        const int BMv = (M == 320) ? 64 : 128;
        dim3 gg(C / 64, M / BMv);
        for (int k = 1; k < 6; ++k) {
            const unsigned short* Xin = Tb + (size_t)(k - 1) * tslot;
            const unsigned short* Pv  = (k >= 2) ? Tb + (size_t)(k - 2) * tslot : nullptr;
            unsigned short* Oo = Tb + (size_t)k * tslot;
            float s = (k == 1) ? 1.f : 2.f;
            float t = (k == 1) ? 0.f : -1.f;
            if (M == 320) gemm_mfma<1><<<gg, 256, 0, stream>>>(Ab, Xin, Pv, Oo, M, s, t);
            else          gemm_mfma<2><<<gg, 256, 0, stream>>>(Ab, Xin, Pv, Oo, M, s, t);
        }
        int blocks = M * 32 / 256;
        if (FIN == 16 && FOUT == 16)      epi_layer<16, 16><<<blocks, 256, 0, stream>>>(Tb, tslot, W, bias, out, M, relu ? 1 : 0);
        else if (FIN == 16 && FOUT == 32) epi_layer<16, 32><<<blocks, 256, 0, stream>>>(Tb, tslot, W, bias, out, M, relu ? 1 : 0);
        else                              epi_layer<32, 16><<<blocks, 256, 0, stream>>>(Tb, tslot, W, bias, out, M, relu ? 1 : 0);
    };

    auto epi0 = [&](int FIN, int FOUT, bool FINAL, const float* tx, const float* W, const float* bias,
                    float* out) {
        int blocks = (NN0 * BATCH + 255) / 256;
        if (FINAL)         epilogue_k<16, 3, true ><<<blocks, 256, 0, stream>>>(tx, W, bias, out, NN0, 1);
        else if (FIN == 3) epilogue_k<3, 16, false><<<blocks, 256, 0, stream>>>(tx, W, bias, out, NN0, 1);
        else               epilogue_k<16, 16, false><<<blocks, 256, 0, stream>>>(tx, W, bias, out, NN0, 1);
    };
    auto sparse_step = [&](int FIN, bool FINAL, const float* txin, const float* txprev, float* txout,
                           const float* W, float* out, float s, float t, int relu) {
        if (FINAL)         sparse_cheb_step<16, 3, true ><<<NN0, 256, 0, stream>>>(rowptr, esrc, ewt, txin, txprev, txout, W, out, s, t, relu);
        else if (FIN == 3) sparse_cheb_step<3, 16, false><<<NN0, 256, 0, stream>>>(rowptr, esrc, ewt, txin, txprev, txout, W, out, s, t, relu);
        else               sparse_cheb_step<16, 16, false><<<NN0, 256, 0, stream>>>(rowptr, esrc, ewt, txin, txprev, txout, W, out, s, t, relu);
    };
    auto cheb_sparse = [&](int FIN, int FOUT, bool FINAL, const float* W, const float* bias,
                           float* h, float* tmp, float* out, bool relu) {
        epi0(FIN, FOUT, FINAL, h, W, bias, out);
        sparse_step(FIN, FINAL, h, nullptr, tmp, W + 1 * FIN * FOUT, out, 1.f, 0.f, 0);
        float* prev = h; float* cur = tmp;
        for (int k = 2; k < 6; ++k) {
            sparse_step(FIN, FINAL, cur, prev, prev, W + k * FIN * FOUT, out, 2.f, -1.f, (k == 5 && relu) ? 1 : 0);
            float* t2 = prev; prev = cur; cur = t2;
        }
    };
    auto pool = [&](const int* idx, const float* w, int M, int cols, const float* in, float* out) {
        pool_kernel<<<((size_t)M * cols + 255) / 256, 256, 0, stream>>>(idx, w, in, out, M, cols);
    };

    // ======================= network =======================
    // encoder
    xcopy_kernel<<<(NN0 * BATCH * 3 + 255) / 256, 256, 0, stream>>>(x, txS0, NN0, 3);
    cheb_sparse(3, 16, false, W_enc[0], b_enc[0], txS0, txS1, bigA, true);
    pool(dn_idx[0], dn_w[0], 5120, 512, bigA, bigB);
    cheb_mfma(adj1b, 5120, 16, 16, W_enc[1], b_enc[1], bigB, bigA, true);
    pool(dn_idx[1], dn_w[1], 1280, 512, bigA, bigB);
    cheb_mfma(adj2b, 1280, 16, 16, W_enc[2], b_enc[2], bigB, bigA, true);
    pool(dn_idx[2], dn_w[2], 320, 512, bigA, bigB);
    cheb_mfma(adj3b, 320, 16, 32, W_enc[3], b_enc[3], bigB, bigA, true);
    pool(dn_idx[3], dn_w[3], 80, 1024, bigA, lat0);
    fc_enc_kernel<<<32, 64, 0, stream>>>(lat0, enc_w, enc_b, zb);
    // decoder
    fc_dec_kernel<<<(80 * 32 * 32 + 255) / 256, 256, 0, stream>>>(zb, dec_w, dec_b, lat1);
    pool(up_idx[3], up_w[3], 320, 1024, lat1, bigA);
    cheb_mfma(adj3b, 320, 32, 16, W_dec[0], b_dec[0], bigA, bigB, true);
    pool(up_idx[2], up_w[2], 1280, 512, bigB, bigA);
    cheb_mfma(adj2b, 1280, 16, 16, W_dec[1], b_dec[1], bigA, bigB, true);
    pool(up_idx[1], up_w[1], 5120, 512, bigB, bigA);
    cheb_mfma(adj1b, 5120, 16, 16, W_dec[2], b_dec[2], bigA, bigB, true);
    pool(up_idx[0], up_w[0], NN0, 512, bigB, bigA);
    cheb_sparse(16, 16, false, W_dec[3], b_dec[3], bigA, bigB, bigC, true);
    cheb_sparse(16, 3, true, W_dec[4], nullptr, bigC, bigA, (float*)d_out, false);
}

// Round 3
// 1737.597 us; speedup vs baseline: 4.0589x; 1.4796x over previous
//
#include <hip/hip_runtime.h>

#define BATCH 32
#define NN0   20480

typedef __attribute__((ext_vector_type(8))) short short8v;
typedef __attribute__((ext_vector_type(4))) float f32x4;

__device__ __forceinline__ float bf2f(unsigned short h) {
    return __uint_as_float(((unsigned int)h) << 16);
}
__device__ __forceinline__ unsigned short f2bf(float x) {
    unsigned int u = __float_as_uint(x);
    u += 0x7fff + ((u >> 16) & 1);   // RNE
    return (unsigned short)(u >> 16);
}
__device__ __forceinline__ unsigned int pk2(float a, float b) {
    return (unsigned int)f2bf(a) | ((unsigned int)f2bf(b) << 16);
}

// ======================= CSR build =======================
__global__ __launch_bounds__(256) void count_kernel(const int* __restrict__ dst, int* __restrict__ cnt, int E) {
    int e = blockIdx.x * 256 + threadIdx.x;
    if (e < E) atomicAdd(&cnt[dst[e]], 1);
}

__global__ __launch_bounds__(256) void scan_kernel(const int* __restrict__ cnt, int* __restrict__ rowptr,
                                                   int* __restrict__ cursor, int n) {
    __shared__ int part[256];
    int tid = threadIdx.x;
    int per = (n + 255) / 256;
    int start = tid * per;
    int end = start + per; if (end > n) end = n; if (start > n) start = n;
    int s = 0;
    for (int i = start; i < end; ++i) s += cnt[i];
    part[tid] = s;
    __syncthreads();
    for (int off = 1; off < 256; off <<= 1) {
        int v = (tid >= off) ? part[tid - off] : 0;
        __syncthreads();
        part[tid] += v;
        __syncthreads();
    }
    int base = (tid == 0) ? 0 : part[tid - 1];
    for (int i = start; i < end; ++i) {
        rowptr[i] = base; cursor[i] = base;
        base += cnt[i];
    }
    if (tid == 255) rowptr[n] = base;
}

__global__ __launch_bounds__(256) void scatter_kernel(const int* __restrict__ src, const int* __restrict__ dst,
                                                      const float* __restrict__ nrm, int* __restrict__ cursor,
                                                      int* __restrict__ esrc, float* __restrict__ ewt,
                                                      int* __restrict__ eid, int E) {
    int e = blockIdx.x * 256 + threadIdx.x;
    if (e >= E) return;
    int p = atomicAdd(&cursor[dst[e]], 1);
    esrc[p] = src[e]; ewt[p] = nrm[e]; eid[p] = e;
}

__global__ __launch_bounds__(256) void sortrows_kernel(const int* __restrict__ rowptr, int* __restrict__ esrc,
                                                       float* __restrict__ ewt, int* __restrict__ eid, int N) {
    int m = blockIdx.x * 256 + threadIdx.x;
    if (m >= N) return;
    int a = rowptr[m], b = rowptr[m + 1];
    for (int i = a + 1; i < b; ++i) {
        int ke = eid[i]; int ks = esrc[i]; float kw = ewt[i];
        int j = i - 1;
        while (j >= a && eid[j] > ke) { eid[j+1]=eid[j]; esrc[j+1]=esrc[j]; ewt[j+1]=ewt[j]; --j; }
        eid[j+1] = ke; esrc[j+1] = ks; ewt[j+1] = kw;
    }
}

// ======================= converts =======================
__global__ __launch_bounds__(256) void convert_flat(const float* __restrict__ in, unsigned short* __restrict__ out,
                                                    size_t n4) {
    for (size_t i = blockIdx.x * 256 + threadIdx.x; i < n4; i += (size_t)gridDim.x * 256) {
        float4 v = reinterpret_cast<const float4*>(in)[i];
        ushort4 o;
        o.x = f2bf(v.x); o.y = f2bf(v.y); o.z = f2bf(v.z); o.w = f2bf(v.w);
        reinterpret_cast<ushort4*>(out)[i] = o;
    }
}

// x fp32 [b*NN0+m][3] -> bf16 node-major [m][b*3+f] (96 cols), LDS transpose per 32-m tile
__global__ __launch_bounds__(256) void xcopy_T(const float* __restrict__ x, unsigned short* __restrict__ out) {
    __shared__ unsigned short sh[32 * 96];
    const int m0 = blockIdx.x * 32;
    const int tid = threadIdx.x;
    const int b = tid >> 3, mi = tid & 7;
#pragma unroll
    for (int ii = 0; ii < 4; ++ii) {
        int mm = mi + ii * 8;
        const float* p = x + ((size_t)b * NN0 + m0 + mm) * 3;
        sh[mm * 96 + b * 3 + 0] = f2bf(p[0]);
        sh[mm * 96 + b * 3 + 1] = f2bf(p[1]);
        sh[mm * 96 + b * 3 + 2] = f2bf(p[2]);
    }
    __syncthreads();
    unsigned int* dst = (unsigned int*)(out + (size_t)m0 * 96);
    const unsigned int* srcp = (const unsigned int*)sh;
    for (int i = tid; i < 32 * 48; i += 256) dst[i] = srcp[i];
}

// ======================= sparse props (bf16) =======================
// COLS=512: one wave per node, 8 cols/lane
__global__ __launch_bounds__(256) void sparse_prop16(const int* __restrict__ rowptr, const int* __restrict__ esrc,
                                                     const float* __restrict__ ewt,
                                                     const unsigned short* __restrict__ Tin,
                                                     const unsigned short* __restrict__ Tprev,
                                                     unsigned short* __restrict__ Tout, float s, float t) {
    int g = blockIdx.x * 256 + threadIdx.x;
    int m = g >> 6, lane = g & 63;
    int e0 = rowptr[m], e1 = rowptr[m + 1];
    float acc[8] = {};
    for (int e = e0; e < e1; ++e) {
        float w = ewt[e];
        short8v v = *reinterpret_cast<const short8v*>(Tin + (size_t)esrc[e] * 512 + lane * 8);
#pragma unroll
        for (int j = 0; j < 8; ++j) acc[j] += w * bf2f((unsigned short)v[j]);
    }
    float r[8];
    if (Tprev) {
        short8v pv = *reinterpret_cast<const short8v*>(Tprev + (size_t)m * 512 + lane * 8);
#pragma unroll
        for (int j = 0; j < 8; ++j) r[j] = s * acc[j] + t * bf2f((unsigned short)pv[j]);
    } else {
#pragma unroll
        for (int j = 0; j < 8; ++j) r[j] = s * acc[j];
    }
    uint4 ov;
    ov.x = pk2(r[0], r[1]); ov.y = pk2(r[2], r[3]); ov.z = pk2(r[4], r[5]); ov.w = pk2(r[6], r[7]);
    *reinterpret_cast<uint4*>(Tout + (size_t)m * 512 + lane * 8) = ov;
}

// COLS=96: thread per (node, col)
__global__ __launch_bounds__(256) void sparse_prop3(const int* __restrict__ rowptr, const int* __restrict__ esrc,
                                                    const float* __restrict__ ewt,
                                                    const unsigned short* __restrict__ Tin,
                                                    const unsigned short* __restrict__ Tprev,
                                                    unsigned short* __restrict__ Tout, float s, float t) {
    int g = blockIdx.x * 256 + threadIdx.x;
    int m = g / 96, c = g - m * 96;
    int e0 = rowptr[m], e1 = rowptr[m + 1];
    float acc = 0.f;
    for (int e = e0; e < e1; ++e)
        acc += ewt[e] * bf2f(Tin[(size_t)esrc[e] * 96 + c]);
    float v = s * acc;
    if (Tprev) v += t * bf2f(Tprev[(size_t)m * 96 + c]);
    Tout[(size_t)m * 96 + c] = f2bf(v);
}

// ======================= fused sparse epilogue -> bf16 node-major =======================
template <int FIN, int FOUT>
__global__ __launch_bounds__(256) void sparse_epi(const unsigned short* __restrict__ S, size_t slot,
                                                  const float* __restrict__ W, const float* __restrict__ bias,
                                                  unsigned short* __restrict__ out, int relu) {
    __shared__ float Ws[6 * FIN * FOUT];
    for (int i = threadIdx.x; i < 6 * FIN * FOUT; i += 256) Ws[i] = W[i];
    __syncthreads();
    int g = blockIdx.x * 256 + threadIdx.x;   // g = m*32 + b
    int m = g >> 5, b = g & 31;
    float oa[FOUT];
#pragma unroll
    for (int o = 0; o < FOUT; ++o) oa[o] = bias ? bias[o] : 0.f;
    for (int k = 0; k < 6; ++k) {
        const unsigned short* p = S + (size_t)k * slot + (size_t)m * (32 * FIN) + b * FIN;
        float xv[FIN];
        if constexpr (FIN == 16) {
            short8v v0 = *reinterpret_cast<const short8v*>(p);
            short8v v1 = *reinterpret_cast<const short8v*>(p + 8);
#pragma unroll
            for (int f = 0; f < 8; ++f) { xv[f] = bf2f((unsigned short)v0[f]); xv[f + 8] = bf2f((unsigned short)v1[f]); }
        } else {
#pragma unroll
            for (int f = 0; f < FIN; ++f) xv[f] = bf2f(p[f]);
        }
#pragma unroll
        for (int f = 0; f < FIN; ++f)
#pragma unroll
            for (int o = 0; o < FOUT; ++o) oa[o] += xv[f] * Ws[(k * FIN + f) * FOUT + o];
    }
    unsigned short* orow = out + (size_t)m * (32 * FOUT) + b * FOUT;
    unsigned int u[FOUT / 2];
#pragma unroll
    for (int o = 0; o < FOUT / 2; ++o) {
        float a = oa[2 * o], c = oa[2 * o + 1];
        if (relu) { a = fmaxf(a, 0.f); c = fmaxf(c, 0.f); }
        u[o] = pk2(a, c);
    }
#pragma unroll
    for (int q = 0; q < FOUT / 8; ++q)
        reinterpret_cast<uint4*>(orow)[q] = make_uint4(u[4 * q], u[4 * q + 1], u[4 * q + 2], u[4 * q + 3]);
}

// final epilogue: FIN=16 -> 3, fp32 d_out at (b*NN0+m)*3, LDS-staged contiguous writes
__global__ __launch_bounds__(256) void sparse_epi_final(const unsigned short* __restrict__ S, size_t slot,
                                                        const float* __restrict__ W, float* __restrict__ dout) {
    __shared__ float Ws[6 * 16 * 3];
    __shared__ float sh[32 * 24];
    for (int i = threadIdx.x; i < 288; i += 256) Ws[i] = W[i];
    __syncthreads();
    const int tid = threadIdx.x;
    const int mm = tid >> 5, b = tid & 31;
    const int m = blockIdx.x * 8 + mm;
    float o0 = 0.f, o1 = 0.f, o2 = 0.f;
    for (int k = 0; k < 6; ++k) {
        const unsigned short* p = S + (size_t)k * slot + (size_t)m * 512 + b * 16;
        short8v v0 = *reinterpret_cast<const short8v*>(p);
        short8v v1 = *reinterpret_cast<const short8v*>(p + 8);
#pragma unroll
        for (int f = 0; f < 16; ++f) {
            float xf = bf2f((unsigned short)(f < 8 ? v0[f] : v1[f - 8]));
            o0 += xf * Ws[(k * 16 + f) * 3 + 0];
            o1 += xf * Ws[(k * 16 + f) * 3 + 1];
            o2 += xf * Ws[(k * 16 + f) * 3 + 2];
        }
    }
    sh[b * 24 + mm * 3 + 0] = o0;
    sh[b * 24 + mm * 3 + 1] = o1;
    sh[b * 24 + mm * 3 + 2] = o2;
    __syncthreads();
    const size_t base = (size_t)blockIdx.x * 24;
    for (int i = tid; i < 768; i += 256) {
        int b2 = i / 24, r = i - b2 * 24;
        dout[(size_t)b2 * (NN0 * 3) + base + r] = sh[i];
    }
}

// ======================= pools =======================
__device__ __forceinline__ float ldv(const float* p) { return *p; }
__device__ __forceinline__ float ldv(const unsigned short* p) { return bf2f(*p); }

// pool + transpose: in [Mold][C] -> out bf16 [C][Mnew]
template <typename TI>
__global__ __launch_bounds__(256) void pool_cT(const TI* __restrict__ in, const int* __restrict__ idx,
                                               const float* __restrict__ w, unsigned short* __restrict__ out,
                                               int C, int Mnew) {
    __shared__ float tile[32][33];
    const int m0 = blockIdx.x * 32, c0 = blockIdx.y * 32;
    const int tx = threadIdx.x & 31, ty = threadIdx.x >> 5;
#pragma unroll
    for (int i = 0; i < 4; ++i) {
        int mn = m0 + ty + i * 8;
        const int* ir = idx + mn * 3; const float* wr = w + mn * 3;
        float v = wr[0] * ldv(in + (size_t)ir[0] * C + c0 + tx)
                + wr[1] * ldv(in + (size_t)ir[1] * C + c0 + tx)
                + wr[2] * ldv(in + (size_t)ir[2] * C + c0 + tx);
        tile[ty + i * 8][tx] = v;
    }
    __syncthreads();
#pragma unroll
    for (int i = 0; i < 4; ++i) {
        int c = c0 + ty + i * 8;
        out[(size_t)c * Mnew + m0 + tx] = f2bf(tile[tx][ty + i * 8]);
    }
}

// up-pool row-major: in bf16 [Mold][512] -> out bf16 [Mnew][512], wave per node
__global__ __launch_bounds__(256) void pool_row16(const unsigned short* __restrict__ in, const int* __restrict__ idx,
                                                  const float* __restrict__ w, unsigned short* __restrict__ out) {
    int g = blockIdx.x * 256 + threadIdx.x;
    int m = g >> 6, lane = g & 63;
    const int* ir = idx + m * 3; const float* wr = w + m * 3;
    short8v a = *reinterpret_cast<const short8v*>(in + (size_t)ir[0] * 512 + lane * 8);
    short8v b = *reinterpret_cast<const short8v*>(in + (size_t)ir[1] * 512 + lane * 8);
    short8v c = *reinterpret_cast<const short8v*>(in + (size_t)ir[2] * 512 + lane * 8);
    float r[8];
#pragma unroll
    for (int j = 0; j < 8; ++j)
        r[j] = wr[0] * bf2f((unsigned short)a[j]) + wr[1] * bf2f((unsigned short)b[j]) + wr[2] * bf2f((unsigned short)c[j]);
    uint4 ov;
    ov.x = pk2(r[0], r[1]); ov.y = pk2(r[2], r[3]); ov.z = pk2(r[4], r[5]); ov.w = pk2(r[6], r[7]);
    *reinterpret_cast<uint4*>(out + (size_t)m * 512 + lane * 8) = ov;
}

// pool to fp32 (lat0): in bf16 [Mold][1024] -> out fp32 [80][1024]
__global__ __launch_bounds__(256) void pool_f32(const unsigned short* __restrict__ in, const int* __restrict__ idx,
                                                const float* __restrict__ w, float* __restrict__ out) {
    int g = blockIdx.x * 256 + threadIdx.x;   // 80*1024
    int m = g >> 10, c = g & 1023;
    const int* ir = idx + m * 3; const float* wr = w + m * 3;
    out[g] = wr[0] * bf2f(in[(size_t)ir[0] * 1024 + c])
           + wr[1] * bf2f(in[(size_t)ir[1] * 1024 + c])
           + wr[2] * bf2f(in[(size_t)ir[2] * 1024 + c]);
}

// ======================= MFMA prop GEMM ==========================
template <int MF>
__global__ __launch_bounds__(256) void gemm_mfma(const unsigned short* __restrict__ Ab,
                                                 const unsigned short* __restrict__ Xb,
                                                 const unsigned short* __restrict__ Pb,
                                                 unsigned short* __restrict__ Ob,
                                                 int Mn, float s, float t) {
    constexpr int BM = MF * 64;
    const int K = Mn;
    __shared__ unsigned short As[BM * 64];
    __shared__ unsigned short Xs[64 * 64];
    const int tid = threadIdx.x;
    const int lane = tid & 63, wid = tid >> 6;
    // XCD-chunked swizzle (all grids have nwg % 8 == 0)
    int lin = blockIdx.y * gridDim.x + blockIdx.x;
    int nwg = gridDim.x * gridDim.y;
    int lin2 = (lin & 7) * (nwg >> 3) + (lin >> 3);
    int by = lin2 / gridDim.x, bx = lin2 - by * gridDim.x;
    const int bm = by * BM, bc = bx * 64;

    f32x4 acc[MF][4] = {};
    constexpr int SEGA = (BM * 64 * 2) / 1024 / 4;

    for (int k0 = 0; k0 < K; k0 += 64) {
        __syncthreads();
#pragma unroll
        for (int i = 0; i < SEGA; ++i) {
            int o = (wid * SEGA + i) * 1024 + lane * 16;
            int row = o >> 7;
            int colb = (o & 127) ^ ((row & 7) << 4);
            const unsigned short* g = Ab + (size_t)(bm + row) * K + k0 + (colb >> 1);
            __builtin_amdgcn_global_load_lds((const __attribute__((address_space(1))) void*)g,
                                             (__attribute__((address_space(3))) void*)((char*)As + (size_t)(wid * SEGA + i) * 1024),
                                             16, 0, 0);
        }
#pragma unroll
        for (int i = 0; i < 2; ++i) {
            int o = (wid * 2 + i) * 1024 + lane * 16;
            int row = o >> 7;
            int colb = (o & 127) ^ ((row & 7) << 4);
            const unsigned short* g = Xb + (size_t)(bc + row) * K + k0 + (colb >> 1);
            __builtin_amdgcn_global_load_lds((const __attribute__((address_space(1))) void*)g,
                                             (__attribute__((address_space(3))) void*)((char*)Xs + (size_t)(wid * 2 + i) * 1024),
                                             16, 0, 0);
        }
        __syncthreads();
#pragma unroll
        for (int kk = 0; kk < 2; ++kk) {
            short8v a[MF], b[4];
#pragma unroll
            for (int mf = 0; mf < MF; ++mf) {
                int r = wid * (MF * 16) + mf * 16 + (lane & 15);
                int cb = kk * 64 + ((lane >> 4) * 16);
                int addr = r * 128 + (cb ^ ((r & 7) << 4));
                a[mf] = *reinterpret_cast<const short8v*>((const char*)As + addr);
            }
#pragma unroll
            for (int cf = 0; cf < 4; ++cf) {
                int r = cf * 16 + (lane & 15);
                int cb = kk * 64 + ((lane >> 4) * 16);
                int addr = r * 128 + (cb ^ ((r & 7) << 4));
                b[cf] = *reinterpret_cast<const short8v*>((const char*)Xs + addr);
            }
#pragma unroll
            for (int mf = 0; mf < MF; ++mf)
#pragma unroll
                for (int cf = 0; cf < 4; ++cf)
                    acc[mf][cf] = __builtin_amdgcn_mfma_f32_16x16x32_bf16(a[mf], b[cf], acc[mf][cf], 0, 0, 0);
        }
    }
#pragma unroll
    for (int mf = 0; mf < MF; ++mf) {
        int m0 = bm + wid * (MF * 16) + mf * 16 + ((lane >> 4) * 4);
#pragma unroll
        for (int cf = 0; cf < 4; ++cf) {
            int c = bc + cf * 16 + (lane & 15);
            size_t base = (size_t)c * Mn + m0;
            float v0 = s * acc[mf][cf][0], v1 = s * acc[mf][cf][1];
            float v2 = s * acc[mf][cf][2], v3 = s * acc[mf][cf][3];
            if (Pb) {
                uint2 pv = *reinterpret_cast<const uint2*>(Pb + base);
                v0 += t * bf2f((unsigned short)(pv.x & 0xffff));
                v1 += t * bf2f((unsigned short)(pv.x >> 16));
                v2 += t * bf2f((unsigned short)(pv.y & 0xffff));
                v3 += t * bf2f((unsigned short)(pv.y >> 16));
            }
            uint2 ov;
            ov.x = pk2(v0, v1); ov.y = pk2(v2, v3);
            *reinterpret_cast<uint2*>(Ob + base) = ov;
        }
    }
}

// ======================= dense fused epilogue -> bf16 [m][32*FOUT] =======================
template <int FIN, int FOUT>
__global__ __launch_bounds__(256) void epi_layer(const unsigned short* __restrict__ Tb, size_t tslot,
                                                 const float* __restrict__ W, const float* __restrict__ bias,
                                                 unsigned short* __restrict__ out, int M) {
    __shared__ float Ws[6 * FIN * FOUT];
    for (int i = threadIdx.x; i < 6 * FIN * FOUT; i += 256) Ws[i] = W[i];
    __syncthreads();
    int g = blockIdx.x * 256 + threadIdx.x;   // g = b*M + m
    int b = g / M, m = g - b * M;
    float oa[FOUT];
#pragma unroll
    for (int o = 0; o < FOUT; ++o) oa[o] = bias[o];
    for (int k = 0; k < 6; ++k) {
        const unsigned short* Tk = Tb + (size_t)k * tslot + (size_t)b * FIN * M + m;
#pragma unroll
        for (int f = 0; f < FIN; ++f) {
            float xf = bf2f(Tk[(size_t)f * M]);
#pragma unroll
            for (int o = 0; o < FOUT; ++o) oa[o] += xf * Ws[(k * FIN + f) * FOUT + o];
        }
    }
    unsigned short* orow = out + (size_t)m * (32 * FOUT) + b * FOUT;
    unsigned int u[FOUT / 2];
#pragma unroll
    for (int o = 0; o < FOUT / 2; ++o)
        u[o] = pk2(fmaxf(oa[2 * o], 0.f), fmaxf(oa[2 * o + 1], 0.f));
#pragma unroll
    for (int q = 0; q < FOUT / 8; ++q)
        reinterpret_cast<uint4*>(orow)[q] = make_uint4(u[4 * q], u[4 * q + 1], u[4 * q + 2], u[4 * q + 3]);
}

// ======================= FCs =======================
__global__ __launch_bounds__(256) void fc_enc_kernel(const float* __restrict__ h, const float* __restrict__ w,
                                                     const float* __restrict__ bias, float* __restrict__ z) {
    __shared__ float sh[256];
    int b = blockIdx.x, o = threadIdx.x & 63, q = threadIdx.x >> 6;
    float acc = 0.f;
    for (int n = q * 20; n < q * 20 + 20; ++n)
#pragma unroll
        for (int f = 0; f < 32; ++f)
            acc += h[((size_t)n * 32 + b) * 32 + f] * w[(size_t)o * 2560 + n * 32 + f];
    sh[threadIdx.x] = acc;
    __syncthreads();
    if (q == 0) z[b * 64 + o] = fmaxf(sh[o] + sh[64 + o] + sh[128 + o] + sh[192 + o] + bias[o], 0.f);
}

__global__ __launch_bounds__(256) void fc_dec_kernel(const float* __restrict__ z, const float* __restrict__ w,
                                                     const float* __restrict__ bias, float* __restrict__ out) {
    int g = blockIdx.x * 256 + threadIdx.x;   // 80*32*32, layout [n][b*32+f]
    if (g >= 80 * 32 * 32) return;
    int f = g % 32; int b = (g / 32) % 32; int n = g / 1024;
    int j = n * 32 + f;
    float acc = bias[j];
    const float* wr = w + (size_t)j * 64;
    const float* zr = z + b * 64;
#pragma unroll
    for (int o = 0; o < 64; ++o) acc += zr[o] * wr[o];
    out[g] = fmaxf(acc, 0.f);
}

// ======================= host orchestration =======================
extern "C" void kernel_launch(void* const* d_in, const int* in_sizes, int n_in,
                              void* d_out, int out_size, void* d_ws, size_t ws_size,
                              hipStream_t stream) {
    (void)n_in; (void)out_size; (void)ws_size;
    const float* x     = (const float*)d_in[0];
    const int*   ei    = (const int*)d_in[1];
    const float* anorm = (const float*)d_in[2];
    const float* adjs[3] = { (const float*)d_in[4], (const float*)d_in[5], (const float*)d_in[6] };
    const int*   dn_idx[4] = { (const int*)d_in[7],  (const int*)d_in[11], (const int*)d_in[15], (const int*)d_in[19] };
    const float* dn_w[4]   = { (const float*)d_in[8],(const float*)d_in[12],(const float*)d_in[16],(const float*)d_in[20] };
    const int*   up_idx[4] = { (const int*)d_in[9],  (const int*)d_in[13], (const int*)d_in[17], (const int*)d_in[21] };
    const float* up_w[4]   = { (const float*)d_in[10],(const float*)d_in[14],(const float*)d_in[18],(const float*)d_in[22] };
    const float* W_enc[4] = { (const float*)d_in[23], (const float*)d_in[25], (const float*)d_in[27], (const float*)d_in[29] };
    const float* b_enc[4] = { (const float*)d_in[24], (const float*)d_in[26], (const float*)d_in[28], (const float*)d_in[30] };
    const float* W_dec[5] = { (const float*)d_in[31], (const float*)d_in[33], (const float*)d_in[35], (const float*)d_in[37], (const float*)d_in[39] };
    const float* b_dec[4] = { (const float*)d_in[32], (const float*)d_in[34], (const float*)d_in[36], (const float*)d_in[38] };
    const float* enc_w = (const float*)d_in[40];
    const float* enc_b = (const float*)d_in[41];
    const float* dec_w = (const float*)d_in[42];
    const float* dec_b = (const float*)d_in[43];
    const int E = in_sizes[2];

    // ---- workspace layout (live-range aliased; ~174 MB) ----
    const size_t SLOT16 = (size_t)NN0 * 512;          // elems (ushort), 20.97 MB
    const size_t SLOT3  = (size_t)NN0 * 96;
    unsigned short* S = (unsigned short*)d_ws;        // 6 slots span 6*SLOT16; slots 3..5 alias Tb/HB/adj1b-head
    unsigned short* Tb = S + 3 * SLOT16;              // 31.5 MB dense shadows (dead when slots 3..5 used)
    unsigned short* HB = Tb + (size_t)6 * 512 * 5120; // 21 MB bf16 node-major inter buffer
    char* p = (char*)(HB + SLOT16);
    unsigned short* adj1b = (unsigned short*)p; p += (size_t)5120 * 5120 * 2;
    unsigned short* adj2b = (unsigned short*)p; p += (size_t)1280 * 1280 * 2;
    unsigned short* adj3b = (unsigned short*)p; p += (size_t)320 * 320 * 2;
    int* rowptr = (int*)p;  p += (NN0 + 4) * sizeof(int);
    int* cnt    = (int*)p;  p += NN0 * sizeof(int);
    int* cursor = (int*)p;  p += NN0 * sizeof(int);
    int* esrc   = (int*)p;  p += (size_t)E * sizeof(int);
    int* eid    = (int*)p;  p += (size_t)E * sizeof(int);
    float* ewt  = (float*)p; p += (size_t)E * sizeof(float);
    float* lat0 = (float*)p; p += 80 * 1024 * sizeof(float);
    float* zb   = (float*)p; p += 32 * 64 * sizeof(float);
    float* lat1 = (float*)p;

    // ---- CSR build (deterministic via per-row sort by edge id) ----
    hipMemsetAsync(cnt, 0, NN0 * sizeof(int), stream);
    count_kernel<<<(E + 255) / 256, 256, 0, stream>>>(ei + E, cnt, E);
    scan_kernel<<<1, 256, 0, stream>>>(cnt, rowptr, cursor, NN0);
    scatter_kernel<<<(E + 255) / 256, 256, 0, stream>>>(ei, ei + E, anorm, cursor, esrc, ewt, eid, E);
    sortrows_kernel<<<(NN0 + 255) / 256, 256, 0, stream>>>(rowptr, esrc, ewt, eid, NN0);

    // ---- adjacency bf16 conversion ----
    convert_flat<<<2048, 256, 0, stream>>>(adjs[0], adj1b, (size_t)5120 * 5120 / 4);
    convert_flat<<<512, 256, 0, stream>>>(adjs[1], adj2b, (size_t)1280 * 1280 / 4);
    convert_flat<<<64, 256, 0, stream>>>(adjs[2], adj3b, (size_t)320 * 320 / 4);

    // ---- helpers ----
    auto dense_layer = [&](const unsigned short* Ab, int M, int FIN, int FOUT,
                           const float* W, const float* bias, unsigned short* HBout) {
        const int C = 32 * FIN;
        const size_t tslot = (size_t)C * M;
        const int BMv = (M == 320) ? 64 : 128;
        dim3 gg(C / 64, M / BMv);
        for (int k = 1; k < 6; ++k) {
            const unsigned short* Xin = Tb + (size_t)(k - 1) * tslot;
            const unsigned short* Pv  = (k >= 2) ? Tb + (size_t)(k - 2) * tslot : nullptr;
            unsigned short* Oo = Tb + (size_t)k * tslot;
            float s = (k == 1) ? 1.f : 2.f;
            float t = (k == 1) ? 0.f : -1.f;
            if (M == 320) gemm_mfma<1><<<gg, 256, 0, stream>>>(Ab, Xin, Pv, Oo, M, s, t);
            else          gemm_mfma<2><<<gg, 256, 0, stream>>>(Ab, Xin, Pv, Oo, M, s, t);
        }
        int blocks = M * 32 / 256;
        if (FIN == 16 && FOUT == 16)      epi_layer<16, 16><<<blocks, 256, 0, stream>>>(Tb, tslot, W, bias, HBout, M);
        else if (FIN == 16 && FOUT == 32) epi_layer<16, 32><<<blocks, 256, 0, stream>>>(Tb, tslot, W, bias, HBout, M);
        else                              epi_layer<32, 16><<<blocks, 256, 0, stream>>>(Tb, tslot, W, bias, HBout, M);
    };
    auto sparse_layer16 = [&](const float* W, const float* bias, int final_relu, unsigned short* out16) {
        // S slot0 pre-filled; props fill slots 1..5; epi -> out16 (bf16 [m][512]) or final
        for (int k = 1; k < 6; ++k) {
            const unsigned short* Tin = S + (size_t)(k - 1) * SLOT16;
            const unsigned short* Pv  = (k >= 2) ? S + (size_t)(k - 2) * SLOT16 : nullptr;
            sparse_prop16<<<NN0 / 4, 256, 0, stream>>>(rowptr, esrc, ewt, Tin, Pv, S + (size_t)k * SLOT16,
                                                       (k == 1) ? 1.f : 2.f, (k == 1) ? 0.f : -1.f);
        }
        if (out16) sparse_epi<16, 16><<<NN0 * 32 / 256, 256, 0, stream>>>(S, SLOT16, W, bias, out16, final_relu);
        else       sparse_epi_final<<<NN0 / 8, 256, 0, stream>>>(S, SLOT16, W, (float*)d_out);
    };

    // ======================= network =======================
    // --- encoder sparse layer (FIN=3) ---
    xcopy_T<<<NN0 / 32, 256, 0, stream>>>(x, S);
    for (int k = 1; k < 6; ++k) {
        const unsigned short* Tin = S + (size_t)(k - 1) * SLOT3;
        const unsigned short* Pv  = (k >= 2) ? S + (size_t)(k - 2) * SLOT3 : nullptr;
        sparse_prop3<<<NN0 * 96 / 256, 256, 0, stream>>>(rowptr, esrc, ewt, Tin, Pv, S + (size_t)k * SLOT3,
                                                         (k == 1) ? 1.f : 2.f, (k == 1) ? 0.f : -1.f);
    }
    sparse_epi<3, 16><<<NN0 * 32 / 256, 256, 0, stream>>>(S, SLOT3, W_enc[0], b_enc[0], HB, 1);
    // --- dense encoder ---
    { dim3 g(5120 / 32, 512 / 32);  pool_cT<unsigned short><<<g, 256, 0, stream>>>(HB, dn_idx[0], dn_w[0], Tb, 512, 5120); }
    dense_layer(adj1b, 5120, 16, 16, W_enc[1], b_enc[1], HB);
    { dim3 g(1280 / 32, 512 / 32);  pool_cT<unsigned short><<<g, 256, 0, stream>>>(HB, dn_idx[1], dn_w[1], Tb, 512, 1280); }
    dense_layer(adj2b, 1280, 16, 16, W_enc[2], b_enc[2], HB);
    { dim3 g(320 / 32, 512 / 32);   pool_cT<unsigned short><<<g, 256, 0, stream>>>(HB, dn_idx[2], dn_w[2], Tb, 512, 320); }
    dense_layer(adj3b, 320, 16, 32, W_enc[3], b_enc[3], HB);
    pool_f32<<<80 * 1024 / 256, 256, 0, stream>>>(HB, dn_idx[3], dn_w[3], lat0);
    fc_enc_kernel<<<32, 256, 0, stream>>>(lat0, enc_w, enc_b, zb);
    // --- decoder ---
    fc_dec_kernel<<<80 * 32 * 32 / 256, 256, 0, stream>>>(zb, dec_w, dec_b, lat1);
    { dim3 g(320 / 32, 1024 / 32);  pool_cT<float><<<g, 256, 0, stream>>>(lat1, up_idx[3], up_w[3], Tb, 1024, 320); }
    dense_layer(adj3b, 320, 32, 16, W_dec[0], b_dec[0], HB);
    { dim3 g(1280 / 32, 512 / 32);  pool_cT<unsigned short><<<g, 256, 0, stream>>>(HB, up_idx[2], up_w[2], Tb, 512, 1280); }
    dense_layer(adj2b, 1280, 16, 16, W_dec[1], b_dec[1], HB);
    { dim3 g(5120 / 32, 512 / 32);  pool_cT<unsigned short><<<g, 256, 0, stream>>>(HB, up_idx[1], up_w[1], Tb, 512, 5120); }
    dense_layer(adj1b, 5120, 16, 16, W_dec[2], b_dec[2], HB);
    pool_row16<<<NN0 / 4, 256, 0, stream>>>(HB, up_idx[0], up_w[0], S);   // -> S slot0
    // --- decoder sparse layers (FIN=16) ---
    sparse_layer16(W_dec[3], b_dec[3], 1, S);          // epi writes slot0 in-place (owner-thread-safe)
    sparse_layer16(W_dec[4], nullptr, 0, nullptr);     // final -> d_out
}

// Round 4
// 1542.469 us; speedup vs baseline: 4.5724x; 1.1265x over previous
//
#include <hip/hip_runtime.h>

#define BATCH 32
#define NN0   20480

typedef __attribute__((ext_vector_type(8))) short short8v;
typedef __attribute__((ext_vector_type(4))) float f32x4;

__device__ __forceinline__ float bf2f(unsigned short h) {
    return __uint_as_float(((unsigned int)h) << 16);
}
__device__ __forceinline__ unsigned short f2bf(float x) {
    unsigned int u = __float_as_uint(x);
    u += 0x7fff + ((u >> 16) & 1);   // RNE
    return (unsigned short)(u >> 16);
}
__device__ __forceinline__ unsigned int pk2(float a, float b) {
    return (unsigned int)f2bf(a) | ((unsigned int)f2bf(b) << 16);
}

// ======================= CSR build =======================
__global__ __launch_bounds__(256) void count_kernel(const int* __restrict__ dst, int* __restrict__ cnt, int E) {
    int e = blockIdx.x * 256 + threadIdx.x;
    if (e < E) atomicAdd(&cnt[dst[e]], 1);
}

__global__ __launch_bounds__(256) void scan_kernel(const int* __restrict__ cnt, int* __restrict__ rowptr,
                                                   int* __restrict__ cursor, int n) {
    __shared__ int part[256];
    int tid = threadIdx.x;
    int per = (n + 255) / 256;
    int start = tid * per;
    int end = start + per; if (end > n) end = n; if (start > n) start = n;
    int s = 0;
    for (int i = start; i < end; ++i) s += cnt[i];
    part[tid] = s;
    __syncthreads();
    for (int off = 1; off < 256; off <<= 1) {
        int v = (tid >= off) ? part[tid - off] : 0;
        __syncthreads();
        part[tid] += v;
        __syncthreads();
    }
    int base = (tid == 0) ? 0 : part[tid - 1];
    for (int i = start; i < end; ++i) {
        rowptr[i] = base; cursor[i] = base;
        base += cnt[i];
    }
    if (tid == 255) rowptr[n] = base;
}

__global__ __launch_bounds__(256) void scatter_kernel(const int* __restrict__ src, const int* __restrict__ dst,
                                                      const float* __restrict__ nrm, int* __restrict__ cursor,
                                                      int* __restrict__ esrc, float* __restrict__ ewt,
                                                      int* __restrict__ eid, int E) {
    int e = blockIdx.x * 256 + threadIdx.x;
    if (e >= E) return;
    int p = atomicAdd(&cursor[dst[e]], 1);
    esrc[p] = src[e]; ewt[p] = nrm[e]; eid[p] = e;
}

__global__ __launch_bounds__(256) void sortrows_kernel(const int* __restrict__ rowptr, int* __restrict__ esrc,
                                                       float* __restrict__ ewt, int* __restrict__ eid, int N) {
    int m = blockIdx.x * 256 + threadIdx.x;
    if (m >= N) return;
    int a = rowptr[m], b = rowptr[m + 1];
    for (int i = a + 1; i < b; ++i) {
        int ke = eid[i]; int ks = esrc[i]; float kw = ewt[i];
        int j = i - 1;
        while (j >= a && eid[j] > ke) { eid[j+1]=eid[j]; esrc[j+1]=esrc[j]; ewt[j+1]=ewt[j]; --j; }
        eid[j+1] = ke; esrc[j+1] = ks; ewt[j+1] = kw;
    }
}

// ======================= converts =======================
__global__ __launch_bounds__(256) void convert_flat(const float* __restrict__ in, unsigned short* __restrict__ out,
                                                    size_t n4) {
    for (size_t i = blockIdx.x * 256 + threadIdx.x; i < n4; i += (size_t)gridDim.x * 256) {
        float4 v = reinterpret_cast<const float4*>(in)[i];
        ushort4 o;
        o.x = f2bf(v.x); o.y = f2bf(v.y); o.z = f2bf(v.z); o.w = f2bf(v.w);
        reinterpret_cast<ushort4*>(out)[i] = o;
    }
}

// x fp32 [b*NN0+m][3] -> bf16 node-major [m][b*3+f] (96 cols), LDS transpose per 32-m tile
__global__ __launch_bounds__(256) void xcopy_T(const float* __restrict__ x, unsigned short* __restrict__ out) {
    __shared__ unsigned short sh[32 * 96];
    const int m0 = blockIdx.x * 32;
    const int tid = threadIdx.x;
    const int b = tid >> 3, mi = tid & 7;
#pragma unroll
    for (int ii = 0; ii < 4; ++ii) {
        int mm = mi + ii * 8;
        const float* p = x + ((size_t)b * NN0 + m0 + mm) * 3;
        sh[mm * 96 + b * 3 + 0] = f2bf(p[0]);
        sh[mm * 96 + b * 3 + 1] = f2bf(p[1]);
        sh[mm * 96 + b * 3 + 2] = f2bf(p[2]);
    }
    __syncthreads();
    unsigned int* dst = (unsigned int*)(out + (size_t)m0 * 96);
    const unsigned int* srcp = (const unsigned int*)sh;
    for (int i = tid; i < 32 * 48; i += 256) dst[i] = srcp[i];
}

// ======================= sparse props (bf16) =======================
__global__ __launch_bounds__(256) void sparse_prop16(const int* __restrict__ rowptr, const int* __restrict__ esrc,
                                                     const float* __restrict__ ewt,
                                                     const unsigned short* __restrict__ Tin,
                                                     const unsigned short* __restrict__ Tprev,
                                                     unsigned short* __restrict__ Tout, float s, float t) {
    int g = blockIdx.x * 256 + threadIdx.x;
    int m = g >> 6, lane = g & 63;
    int e0 = rowptr[m], e1 = rowptr[m + 1];
    float acc[8] = {};
    for (int e = e0; e < e1; ++e) {
        float w = ewt[e];
        short8v v = *reinterpret_cast<const short8v*>(Tin + (size_t)esrc[e] * 512 + lane * 8);
#pragma unroll
        for (int j = 0; j < 8; ++j) acc[j] += w * bf2f((unsigned short)v[j]);
    }
    float r[8];
    if (Tprev) {
        short8v pv = *reinterpret_cast<const short8v*>(Tprev + (size_t)m * 512 + lane * 8);
#pragma unroll
        for (int j = 0; j < 8; ++j) r[j] = s * acc[j] + t * bf2f((unsigned short)pv[j]);
    } else {
#pragma unroll
        for (int j = 0; j < 8; ++j) r[j] = s * acc[j];
    }
    uint4 ov;
    ov.x = pk2(r[0], r[1]); ov.y = pk2(r[2], r[3]); ov.z = pk2(r[4], r[5]); ov.w = pk2(r[6], r[7]);
    *reinterpret_cast<uint4*>(Tout + (size_t)m * 512 + lane * 8) = ov;
}

__global__ __launch_bounds__(256) void sparse_prop3(const int* __restrict__ rowptr, const int* __restrict__ esrc,
                                                    const float* __restrict__ ewt,
                                                    const unsigned short* __restrict__ Tin,
                                                    const unsigned short* __restrict__ Tprev,
                                                    unsigned short* __restrict__ Tout, float s, float t) {
    int g = blockIdx.x * 256 + threadIdx.x;
    int m = g / 96, c = g - m * 96;
    int e0 = rowptr[m], e1 = rowptr[m + 1];
    float acc = 0.f;
    for (int e = e0; e < e1; ++e)
        acc += ewt[e] * bf2f(Tin[(size_t)esrc[e] * 96 + c]);
    float v = s * acc;
    if (Tprev) v += t * bf2f(Tprev[(size_t)m * 96 + c]);
    Tout[(size_t)m * 96 + c] = f2bf(v);
}

// ======================= fused sparse epilogue -> bf16 node-major =======================
template <int FIN, int FOUT>
__global__ __launch_bounds__(256) void sparse_epi(const unsigned short* __restrict__ S, size_t slot,
                                                  const float* __restrict__ W, const float* __restrict__ bias,
                                                  unsigned short* __restrict__ out, int relu) {
    __shared__ float Ws[6 * FIN * FOUT];
    for (int i = threadIdx.x; i < 6 * FIN * FOUT; i += 256) Ws[i] = W[i];
    __syncthreads();
    int g = blockIdx.x * 256 + threadIdx.x;   // g = m*32 + b
    int m = g >> 5, b = g & 31;
    float oa[FOUT];
#pragma unroll
    for (int o = 0; o < FOUT; ++o) oa[o] = bias ? bias[o] : 0.f;
    for (int k = 0; k < 6; ++k) {
        const unsigned short* p = S + (size_t)k * slot + (size_t)m * (32 * FIN) + b * FIN;
        float xv[FIN];
        if constexpr (FIN == 16) {
            short8v v0 = *reinterpret_cast<const short8v*>(p);
            short8v v1 = *reinterpret_cast<const short8v*>(p + 8);
#pragma unroll
            for (int f = 0; f < 8; ++f) { xv[f] = bf2f((unsigned short)v0[f]); xv[f + 8] = bf2f((unsigned short)v1[f]); }
        } else {
#pragma unroll
            for (int f = 0; f < FIN; ++f) xv[f] = bf2f(p[f]);
        }
#pragma unroll
        for (int f = 0; f < FIN; ++f)
#pragma unroll
            for (int o = 0; o < FOUT; ++o) oa[o] += xv[f] * Ws[(k * FIN + f) * FOUT + o];
    }
    unsigned short* orow = out + (size_t)m * (32 * FOUT) + b * FOUT;
    unsigned int u[FOUT / 2];
#pragma unroll
    for (int o = 0; o < FOUT / 2; ++o) {
        float a = oa[2 * o], c = oa[2 * o + 1];
        if (relu) { a = fmaxf(a, 0.f); c = fmaxf(c, 0.f); }
        u[o] = pk2(a, c);
    }
#pragma unroll
    for (int q = 0; q < FOUT / 8; ++q)
        reinterpret_cast<uint4*>(orow)[q] = make_uint4(u[4 * q], u[4 * q + 1], u[4 * q + 2], u[4 * q + 3]);
}

// final epilogue: FIN=16 -> 3, fp32 d_out at (b*NN0+m)*3, LDS-staged contiguous writes
__global__ __launch_bounds__(256) void sparse_epi_final(const unsigned short* __restrict__ S, size_t slot,
                                                        const float* __restrict__ W, float* __restrict__ dout) {
    __shared__ float Ws[6 * 16 * 3];
    __shared__ float sh[32 * 24];
    for (int i = threadIdx.x; i < 288; i += 256) Ws[i] = W[i];
    __syncthreads();
    const int tid = threadIdx.x;
    const int mm = tid >> 5, b = tid & 31;
    const int m = blockIdx.x * 8 + mm;
    float o0 = 0.f, o1 = 0.f, o2 = 0.f;
    for (int k = 0; k < 6; ++k) {
        const unsigned short* p = S + (size_t)k * slot + (size_t)m * 512 + b * 16;
        short8v v0 = *reinterpret_cast<const short8v*>(p);
        short8v v1 = *reinterpret_cast<const short8v*>(p + 8);
#pragma unroll
        for (int f = 0; f < 16; ++f) {
            float xf = bf2f((unsigned short)(f < 8 ? v0[f] : v1[f - 8]));
            o0 += xf * Ws[(k * 16 + f) * 3 + 0];
            o1 += xf * Ws[(k * 16 + f) * 3 + 1];
            o2 += xf * Ws[(k * 16 + f) * 3 + 2];
        }
    }
    sh[b * 24 + mm * 3 + 0] = o0;
    sh[b * 24 + mm * 3 + 1] = o1;
    sh[b * 24 + mm * 3 + 2] = o2;
    __syncthreads();
    const size_t base = (size_t)blockIdx.x * 24;
    for (int i = tid; i < 768; i += 256) {
        int b2 = i / 24, r = i - b2 * 24;
        dout[(size_t)b2 * (NN0 * 3) + base + r] = sh[i];
    }
}

// ======================= pools =======================
__device__ __forceinline__ float ldv(const float* p) { return *p; }
__device__ __forceinline__ float ldv(const unsigned short* p) { return bf2f(*p); }

template <typename TI>
__global__ __launch_bounds__(256) void pool_cT(const TI* __restrict__ in, const int* __restrict__ idx,
                                               const float* __restrict__ w, unsigned short* __restrict__ out,
                                               int C, int Mnew) {
    __shared__ float tile[32][33];
    const int m0 = blockIdx.x * 32, c0 = blockIdx.y * 32;
    const int tx = threadIdx.x & 31, ty = threadIdx.x >> 5;
#pragma unroll
    for (int i = 0; i < 4; ++i) {
        int mn = m0 + ty + i * 8;
        const int* ir = idx + mn * 3; const float* wr = w + mn * 3;
        float v = wr[0] * ldv(in + (size_t)ir[0] * C + c0 + tx)
                + wr[1] * ldv(in + (size_t)ir[1] * C + c0 + tx)
                + wr[2] * ldv(in + (size_t)ir[2] * C + c0 + tx);
        tile[ty + i * 8][tx] = v;
    }
    __syncthreads();
#pragma unroll
    for (int i = 0; i < 4; ++i) {
        int c = c0 + ty + i * 8;
        out[(size_t)c * Mnew + m0 + tx] = f2bf(tile[tx][ty + i * 8]);
    }
}

__global__ __launch_bounds__(256) void pool_row16(const unsigned short* __restrict__ in, const int* __restrict__ idx,
                                                  const float* __restrict__ w, unsigned short* __restrict__ out) {
    int g = blockIdx.x * 256 + threadIdx.x;
    int m = g >> 6, lane = g & 63;
    const int* ir = idx + m * 3; const float* wr = w + m * 3;
    short8v a = *reinterpret_cast<const short8v*>(in + (size_t)ir[0] * 512 + lane * 8);
    short8v b = *reinterpret_cast<const short8v*>(in + (size_t)ir[1] * 512 + lane * 8);
    short8v c = *reinterpret_cast<const short8v*>(in + (size_t)ir[2] * 512 + lane * 8);
    float r[8];
#pragma unroll
    for (int j = 0; j < 8; ++j)
        r[j] = wr[0] * bf2f((unsigned short)a[j]) + wr[1] * bf2f((unsigned short)b[j]) + wr[2] * bf2f((unsigned short)c[j]);
    uint4 ov;
    ov.x = pk2(r[0], r[1]); ov.y = pk2(r[2], r[3]); ov.z = pk2(r[4], r[5]); ov.w = pk2(r[6], r[7]);
    *reinterpret_cast<uint4*>(out + (size_t)m * 512 + lane * 8) = ov;
}

__global__ __launch_bounds__(256) void pool_f32(const unsigned short* __restrict__ in, const int* __restrict__ idx,
                                                const float* __restrict__ w, float* __restrict__ out) {
    int g = blockIdx.x * 256 + threadIdx.x;   // 80*1024
    int m = g >> 10, c = g & 1023;
    const int* ir = idx + m * 3; const float* wr = w + m * 3;
    out[g] = wr[0] * bf2f(in[(size_t)ir[0] * 1024 + c])
           + wr[1] * bf2f(in[(size_t)ir[1] * 1024 + c])
           + wr[2] * bf2f(in[(size_t)ir[2] * 1024 + c]);
}

// ======================= MFMA prop GEMM (optionally split-K) ==========================
// SPLIT: grid.z = K-chunk idx; writes fp32 partial Pf[z][C][M]. else: full epilogue to Ob.
template <int MF, bool SPLIT>
__global__ __launch_bounds__(256) void gemm_mfma(const unsigned short* __restrict__ Ab,
                                                 const unsigned short* __restrict__ Xb,
                                                 const unsigned short* __restrict__ Pb,
                                                 unsigned short* __restrict__ Ob,
                                                 float* __restrict__ Pf,
                                                 int Mn, int KC, float s, float t) {
    constexpr int BM = MF * 64;
    __shared__ unsigned short As[BM * 64];
    __shared__ unsigned short Xs[64 * 64];
    const int tid = threadIdx.x;
    const int lane = tid & 63, wid = tid >> 6;
    // XCD-chunked swizzle over x-y (nwg % 8 == 0 for all our grids)
    int lin = blockIdx.y * gridDim.x + blockIdx.x;
    int nwg = gridDim.x * gridDim.y;
    int lin2 = (lin & 7) * (nwg >> 3) + (lin >> 3);
    int by = lin2 / gridDim.x, bx = lin2 - by * gridDim.x;
    const int bm = by * BM, bc = bx * 64;
    const int kbase = SPLIT ? blockIdx.z * KC : 0;

    f32x4 acc[MF][4] = {};
    constexpr int SEGA = (BM * 64 * 2) / 1024 / 4;

    for (int k0 = kbase; k0 < kbase + KC; k0 += 64) {
        __syncthreads();
#pragma unroll
        for (int i = 0; i < SEGA; ++i) {
            int o = (wid * SEGA + i) * 1024 + lane * 16;
            int row = o >> 7;
            int colb = (o & 127) ^ ((row & 7) << 4);
            const unsigned short* g = Ab + (size_t)(bm + row) * Mn + k0 + (colb >> 1);
            __builtin_amdgcn_global_load_lds((const __attribute__((address_space(1))) void*)g,
                                             (__attribute__((address_space(3))) void*)((char*)As + (size_t)(wid * SEGA + i) * 1024),
                                             16, 0, 0);
        }
#pragma unroll
        for (int i = 0; i < 2; ++i) {
            int o = (wid * 2 + i) * 1024 + lane * 16;
            int row = o >> 7;
            int colb = (o & 127) ^ ((row & 7) << 4);
            const unsigned short* g = Xb + (size_t)(bc + row) * Mn + k0 + (colb >> 1);
            __builtin_amdgcn_global_load_lds((const __attribute__((address_space(1))) void*)g,
                                             (__attribute__((address_space(3))) void*)((char*)Xs + (size_t)(wid * 2 + i) * 1024),
                                             16, 0, 0);
        }
        __syncthreads();
#pragma unroll
        for (int kk = 0; kk < 2; ++kk) {
            short8v a[MF], b[4];
#pragma unroll
            for (int mf = 0; mf < MF; ++mf) {
                int r = wid * (MF * 16) + mf * 16 + (lane & 15);
                int cb = kk * 64 + ((lane >> 4) * 16);
                int addr = r * 128 + (cb ^ ((r & 7) << 4));
                a[mf] = *reinterpret_cast<const short8v*>((const char*)As + addr);
            }
#pragma unroll
            for (int cf = 0; cf < 4; ++cf) {
                int r = cf * 16 + (lane & 15);
                int cb = kk * 64 + ((lane >> 4) * 16);
                int addr = r * 128 + (cb ^ ((r & 7) << 4));
                b[cf] = *reinterpret_cast<const short8v*>((const char*)Xs + addr);
            }
#pragma unroll
            for (int mf = 0; mf < MF; ++mf)
#pragma unroll
                for (int cf = 0; cf < 4; ++cf)
                    acc[mf][cf] = __builtin_amdgcn_mfma_f32_16x16x32_bf16(a[mf], b[cf], acc[mf][cf], 0, 0, 0);
        }
    }
#pragma unroll
    for (int mf = 0; mf < MF; ++mf) {
        int m0 = bm + wid * (MF * 16) + mf * 16 + ((lane >> 4) * 4);
#pragma unroll
        for (int cf = 0; cf < 4; ++cf) {
            int c = bc + cf * 16 + (lane & 15);
            size_t base = (size_t)c * Mn + m0;
            if constexpr (SPLIT) {
                size_t zbase = (size_t)blockIdx.z * (size_t)(gridDim.x * 64) * (size_t)Mn;
                *reinterpret_cast<float4*>(Pf + zbase + base) =
                    make_float4(acc[mf][cf][0], acc[mf][cf][1], acc[mf][cf][2], acc[mf][cf][3]);
            } else {
                float v0 = s * acc[mf][cf][0], v1 = s * acc[mf][cf][1];
                float v2 = s * acc[mf][cf][2], v3 = s * acc[mf][cf][3];
                if (Pb) {
                    uint2 pv = *reinterpret_cast<const uint2*>(Pb + base);
                    v0 += t * bf2f((unsigned short)(pv.x & 0xffff));
                    v1 += t * bf2f((unsigned short)(pv.x >> 16));
                    v2 += t * bf2f((unsigned short)(pv.y & 0xffff));
                    v3 += t * bf2f((unsigned short)(pv.y >> 16));
                }
                uint2 ov;
                ov.x = pk2(v0, v1); ov.y = pk2(v2, v3);
                *reinterpret_cast<uint2*>(Ob + base) = ov;
            }
        }
    }
}

// split-K reduce: Out[g] = bf16( s*sum_ks Pf[ks][g] + t*Prev[g] ), 4 elems/thread
__global__ __launch_bounds__(256) void sk_reduce(const float* __restrict__ Pf,
                                                 const unsigned short* __restrict__ Prev,
                                                 unsigned short* __restrict__ Out,
                                                 int n4, int KS, float s, float t) {
    int g = blockIdx.x * 256 + threadIdx.x;
    if (g >= n4) return;
    float4 a = reinterpret_cast<const float4*>(Pf)[g];
    for (int ks = 1; ks < KS; ++ks) {
        float4 b = reinterpret_cast<const float4*>(Pf)[(size_t)ks * n4 + g];
        a.x += b.x; a.y += b.y; a.z += b.z; a.w += b.w;
    }
    float v0 = s * a.x, v1 = s * a.y, v2 = s * a.z, v3 = s * a.w;
    if (Prev) {
        uint2 pv = reinterpret_cast<const uint2*>(Prev)[g];
        v0 += t * bf2f((unsigned short)(pv.x & 0xffff));
        v1 += t * bf2f((unsigned short)(pv.x >> 16));
        v2 += t * bf2f((unsigned short)(pv.y & 0xffff));
        v3 += t * bf2f((unsigned short)(pv.y >> 16));
    }
    uint2 ov;
    ov.x = pk2(v0, v1); ov.y = pk2(v2, v3);
    reinterpret_cast<uint2*>(Out)[g] = ov;
}

// ======================= dense fused epilogue -> bf16 [m][32*FOUT] =======================
template <int FIN, int FOUT>
__global__ __launch_bounds__(256) void epi_layer(const unsigned short* __restrict__ Tb, size_t tslot,
                                                 const float* __restrict__ W, const float* __restrict__ bias,
                                                 unsigned short* __restrict__ out, int M) {
    __shared__ float Ws[6 * FIN * FOUT];
    for (int i = threadIdx.x; i < 6 * FIN * FOUT; i += 256) Ws[i] = W[i];
    __syncthreads();
    int g = blockIdx.x * 256 + threadIdx.x;   // g = b*M + m
    int b = g / M, m = g - b * M;
    float oa[FOUT];
#pragma unroll
    for (int o = 0; o < FOUT; ++o) oa[o] = bias[o];
    for (int k = 0; k < 6; ++k) {
        const unsigned short* Tk = Tb + (size_t)k * tslot + (size_t)b * FIN * M + m;
#pragma unroll
        for (int f = 0; f < FIN; ++f) {
            float xf = bf2f(Tk[(size_t)f * M]);
#pragma unroll
            for (int o = 0; o < FOUT; ++o) oa[o] += xf * Ws[(k * FIN + f) * FOUT + o];
        }
    }
    unsigned short* orow = out + (size_t)m * (32 * FOUT) + b * FOUT;
    unsigned int u[FOUT / 2];
#pragma unroll
    for (int o = 0; o < FOUT / 2; ++o)
        u[o] = pk2(fmaxf(oa[2 * o], 0.f), fmaxf(oa[2 * o + 1], 0.f));
#pragma unroll
    for (int q = 0; q < FOUT / 8; ++q)
        reinterpret_cast<uint4*>(orow)[q] = make_uint4(u[4 * q], u[4 * q + 1], u[4 * q + 2], u[4 * q + 3]);
}

// ======================= FCs =======================
__global__ __launch_bounds__(256) void fc_enc_kernel(const float* __restrict__ h, const float* __restrict__ w,
                                                     const float* __restrict__ bias, float* __restrict__ z) {
    __shared__ float sh[256];
    int b = blockIdx.x, o = threadIdx.x & 63, q = threadIdx.x >> 6;
    float acc = 0.f;
    for (int n = q * 20; n < q * 20 + 20; ++n)
#pragma unroll
        for (int f = 0; f < 32; ++f)
            acc += h[((size_t)n * 32 + b) * 32 + f] * w[(size_t)o * 2560 + n * 32 + f];
    sh[threadIdx.x] = acc;
    __syncthreads();
    if (q == 0) z[b * 64 + o] = fmaxf(sh[o] + sh[64 + o] + sh[128 + o] + sh[192 + o] + bias[o], 0.f);
}

__global__ __launch_bounds__(256) void fc_dec_kernel(const float* __restrict__ z, const float* __restrict__ w,
                                                     const float* __restrict__ bias, float* __restrict__ out) {
    int g = blockIdx.x * 256 + threadIdx.x;   // 80*32*32, layout [n][b*32+f]
    if (g >= 80 * 32 * 32) return;
    int f = g % 32; int b = (g / 32) % 32; int n = g / 1024;
    int j = n * 32 + f;
    float acc = bias[j];
    const float* wr = w + (size_t)j * 64;
    const float* zr = z + b * 64;
#pragma unroll
    for (int o = 0; o < 64; ++o) acc += zr[o] * wr[o];
    out[g] = fmaxf(acc, 0.f);
}

// ======================= host orchestration =======================
extern "C" void kernel_launch(void* const* d_in, const int* in_sizes, int n_in,
                              void* d_out, int out_size, void* d_ws, size_t ws_size,
                              hipStream_t stream) {
    (void)n_in; (void)out_size; (void)ws_size;
    const float* x     = (const float*)d_in[0];
    const int*   ei    = (const int*)d_in[1];
    const float* anorm = (const float*)d_in[2];
    const float* adjs[3] = { (const float*)d_in[4], (const float*)d_in[5], (const float*)d_in[6] };
    const int*   dn_idx[4] = { (const int*)d_in[7],  (const int*)d_in[11], (const int*)d_in[15], (const int*)d_in[19] };
    const float* dn_w[4]   = { (const float*)d_in[8],(const float*)d_in[12],(const float*)d_in[16],(const float*)d_in[20] };
    const int*   up_idx[4] = { (const int*)d_in[9],  (const int*)d_in[13], (const int*)d_in[17], (const int*)d_in[21] };
    const float* up_w[4]   = { (const float*)d_in[10],(const float*)d_in[14],(const float*)d_in[18],(const float*)d_in[22] };
    const float* W_enc[4] = { (const float*)d_in[23], (const float*)d_in[25], (const float*)d_in[27], (const float*)d_in[29] };
    const float* b_enc[4] = { (const float*)d_in[24], (const float*)d_in[26], (const float*)d_in[28], (const float*)d_in[30] };
    const float* W_dec[5] = { (const float*)d_in[31], (const float*)d_in[33], (const float*)d_in[35], (const float*)d_in[37], (const float*)d_in[39] };
    const float* b_dec[4] = { (const float*)d_in[32], (const float*)d_in[34], (const float*)d_in[36], (const float*)d_in[38] };
    const float* enc_w = (const float*)d_in[40];
    const float* enc_b = (const float*)d_in[41];
    const float* dec_w = (const float*)d_in[42];
    const float* dec_b = (const float*)d_in[43];
    const int E = in_sizes[2];

    // ---- workspace layout (live-range aliased) ----
    const size_t SLOT16 = (size_t)NN0 * 512;          // ushort elems, 21 MB
    const size_t SLOT3  = (size_t)NN0 * 96;
    unsigned short* S = (unsigned short*)d_ws;        // sparse slots; also split-K partial region (disjoint in time)
    float* Pf = (float*)d_ws;                         // fp32 partials during dense layers (<= 42 MB < 3*SLOT16)
    unsigned short* Tb = S + 3 * SLOT16;
    unsigned short* HB = Tb + (size_t)6 * 512 * 5120;
    char* p = (char*)(HB + SLOT16);
    unsigned short* adj1b = (unsigned short*)p; p += (size_t)5120 * 5120 * 2;
    unsigned short* adj2b = (unsigned short*)p; p += (size_t)1280 * 1280 * 2;
    unsigned short* adj3b = (unsigned short*)p; p += (size_t)320 * 320 * 2;
    int* rowptr = (int*)p;  p += (NN0 + 4) * sizeof(int);
    int* cnt    = (int*)p;  p += NN0 * sizeof(int);
    int* cursor = (int*)p;  p += NN0 * sizeof(int);
    int* esrc   = (int*)p;  p += (size_t)E * sizeof(int);
    int* eid    = (int*)p;  p += (size_t)E * sizeof(int);
    float* ewt  = (float*)p; p += (size_t)E * sizeof(float);
    float* lat0 = (float*)p; p += 80 * 1024 * sizeof(float);
    float* zb   = (float*)p; p += 32 * 64 * sizeof(float);
    float* lat1 = (float*)p;

    // ---- CSR build (deterministic via per-row sort by edge id) ----
    hipMemsetAsync(cnt, 0, NN0 * sizeof(int), stream);
    count_kernel<<<(E + 255) / 256, 256, 0, stream>>>(ei + E, cnt, E);
    scan_kernel<<<1, 256, 0, stream>>>(cnt, rowptr, cursor, NN0);
    scatter_kernel<<<(E + 255) / 256, 256, 0, stream>>>(ei, ei + E, anorm, cursor, esrc, ewt, eid, E);
    sortrows_kernel<<<(NN0 + 255) / 256, 256, 0, stream>>>(rowptr, esrc, ewt, eid, NN0);

    // ---- adjacency bf16 conversion ----
    convert_flat<<<2048, 256, 0, stream>>>(adjs[0], adj1b, (size_t)5120 * 5120 / 4);
    convert_flat<<<512, 256, 0, stream>>>(adjs[1], adj2b, (size_t)1280 * 1280 / 4);
    convert_flat<<<64, 256, 0, stream>>>(adjs[2], adj3b, (size_t)320 * 320 / 4);

    // ---- helpers ----
    auto dense_layer = [&](const unsigned short* Ab, int M, int FIN, int FOUT,
                           const float* W, const float* bias, unsigned short* HBout) {
        const int C = 32 * FIN;
        const size_t tslot = (size_t)C * M;
        const int CM4 = (int)(tslot / 4);
        int KS, KC, BMv, MFv;
        if (M == 5120)      { BMv = 128; MFv = 2; KS = 4; KC = 1280; }
        else if (M == 1280) { BMv = 64;  MFv = 1; KS = 4; KC = 320;  }
        else                { BMv = 64;  MFv = 1; KS = 1; KC = M;    }
        dim3 gg(C / 64, M / BMv, KS);
        for (int k = 1; k < 6; ++k) {
            const unsigned short* Xin = Tb + (size_t)(k - 1) * tslot;
            const unsigned short* Pv  = (k >= 2) ? Tb + (size_t)(k - 2) * tslot : nullptr;
            unsigned short* Oo = Tb + (size_t)k * tslot;
            float s = (k == 1) ? 1.f : 2.f;
            float t = (k == 1) ? 0.f : -1.f;
            if (KS > 1) {
                if (MFv == 2) gemm_mfma<2, true><<<gg, 256, 0, stream>>>(Ab, Xin, nullptr, nullptr, Pf, M, KC, s, t);
                else          gemm_mfma<1, true><<<gg, 256, 0, stream>>>(Ab, Xin, nullptr, nullptr, Pf, M, KC, s, t);
                sk_reduce<<<(CM4 + 255) / 256, 256, 0, stream>>>(Pf, Pv, Oo, CM4, KS, s, t);
            } else {
                gemm_mfma<1, false><<<gg, 256, 0, stream>>>(Ab, Xin, Pv, Oo, nullptr, M, KC, s, t);
            }
        }
        int blocks = M * 32 / 256;
        if (FIN == 16 && FOUT == 16)      epi_layer<16, 16><<<blocks, 256, 0, stream>>>(Tb, tslot, W, bias, HBout, M);
        else if (FIN == 16 && FOUT == 32) epi_layer<16, 32><<<blocks, 256, 0, stream>>>(Tb, tslot, W, bias, HBout, M);
        else                              epi_layer<32, 16><<<blocks, 256, 0, stream>>>(Tb, tslot, W, bias, HBout, M);
    };
    auto sparse_layer16 = [&](const float* W, const float* bias, int final_relu, unsigned short* out16) {
        for (int k = 1; k < 6; ++k) {
            const unsigned short* Tin = S + (size_t)(k - 1) * SLOT16;
            const unsigned short* Pv  = (k >= 2) ? S + (size_t)(k - 2) * SLOT16 : nullptr;
            sparse_prop16<<<NN0 / 4, 256, 0, stream>>>(rowptr, esrc, ewt, Tin, Pv, S + (size_t)k * SLOT16,
                                                       (k == 1) ? 1.f : 2.f, (k == 1) ? 0.f : -1.f);
        }
        if (out16) sparse_epi<16, 16><<<NN0 * 32 / 256, 256, 0, stream>>>(S, SLOT16, W, bias, out16, final_relu);
        else       sparse_epi_final<<<NN0 / 8, 256, 0, stream>>>(S, SLOT16, W, (float*)d_out);
    };

    // ======================= network =======================
    // --- encoder sparse layer (FIN=3) ---
    xcopy_T<<<NN0 / 32, 256, 0, stream>>>(x, S);
    for (int k = 1; k < 6; ++k) {
        const unsigned short* Tin = S + (size_t)(k - 1) * SLOT3;
        const unsigned short* Pv  = (k >= 2) ? S + (size_t)(k - 2) * SLOT3 : nullptr;
        sparse_prop3<<<NN0 * 96 / 256, 256, 0, stream>>>(rowptr, esrc, ewt, Tin, Pv, S + (size_t)k * SLOT3,
                                                         (k == 1) ? 1.f : 2.f, (k == 1) ? 0.f : -1.f);
    }
    sparse_epi<3, 16><<<NN0 * 32 / 256, 256, 0, stream>>>(S, SLOT3, W_enc[0], b_enc[0], HB, 1);
    // --- dense encoder ---
    { dim3 g(5120 / 32, 512 / 32);  pool_cT<unsigned short><<<g, 256, 0, stream>>>(HB, dn_idx[0], dn_w[0], Tb, 512, 5120); }
    dense_layer(adj1b, 5120, 16, 16, W_enc[1], b_enc[1], HB);
    { dim3 g(1280 / 32, 512 / 32);  pool_cT<unsigned short><<<g, 256, 0, stream>>>(HB, dn_idx[1], dn_w[1], Tb, 512, 1280); }
    dense_layer(adj2b, 1280, 16, 16, W_enc[2], b_enc[2], HB);
    { dim3 g(320 / 32, 512 / 32);   pool_cT<unsigned short><<<g, 256, 0, stream>>>(HB, dn_idx[2], dn_w[2], Tb, 512, 320); }
    dense_layer(adj3b, 320, 16, 32, W_enc[3], b_enc[3], HB);
    pool_f32<<<80 * 1024 / 256, 256, 0, stream>>>(HB, dn_idx[3], dn_w[3], lat0);
    fc_enc_kernel<<<32, 256, 0, stream>>>(lat0, enc_w, enc_b, zb);
    // --- decoder ---
    fc_dec_kernel<<<80 * 32 * 32 / 256, 256, 0, stream>>>(zb, dec_w, dec_b, lat1);
    { dim3 g(320 / 32, 1024 / 32);  pool_cT<float><<<g, 256, 0, stream>>>(lat1, up_idx[3], up_w[3], Tb, 1024, 320); }
    dense_layer(adj3b, 320, 32, 16, W_dec[0], b_dec[0], HB);
    { dim3 g(1280 / 32, 512 / 32);  pool_cT<unsigned short><<<g, 256, 0, stream>>>(HB, up_idx[2], up_w[2], Tb, 512, 1280); }
    dense_layer(adj2b, 1280, 16, 16, W_dec[1], b_dec[1], HB);
    { dim3 g(5120 / 32, 512 / 32);  pool_cT<unsigned short><<<g, 256, 0, stream>>>(HB, up_idx[1], up_w[1], Tb, 512, 5120); }
    dense_layer(adj1b, 5120, 16, 16, W_dec[2], b_dec[2], HB);
    pool_row16<<<NN0 / 4, 256, 0, stream>>>(HB, up_idx[0], up_w[0], S);   // -> S slot0
    // --- decoder sparse layers (FIN=16) ---
    sparse_layer16(W_dec[3], b_dec[3], 1, S);          // epi writes slot0 in-place (owner-thread-safe)
    sparse_layer16(W_dec[4], nullptr, 0, nullptr);     // final -> d_out
}

// Round 5
// 1482.166 us; speedup vs baseline: 4.7584x; 1.0407x over previous
//
#include <hip/hip_runtime.h>

#define BATCH 32
#define NN0   20480

typedef __attribute__((ext_vector_type(8))) short short8v;
typedef __attribute__((ext_vector_type(4))) float f32x4;

__device__ __forceinline__ float bf2f(unsigned short h) {
    return __uint_as_float(((unsigned int)h) << 16);
}
__device__ __forceinline__ unsigned short f2bf(float x) {
    unsigned int u = __float_as_uint(x);
    u += 0x7fff + ((u >> 16) & 1);   // RNE
    return (unsigned short)(u >> 16);
}
__device__ __forceinline__ unsigned int pk2(float a, float b) {
    return (unsigned int)f2bf(a) | ((unsigned int)f2bf(b) << 16);
}

// ======================= CSR build =======================
__global__ __launch_bounds__(256) void count_kernel(const int* __restrict__ dst, int* __restrict__ cnt, int E) {
    int e = blockIdx.x * 256 + threadIdx.x;
    if (e < E) atomicAdd(&cnt[dst[e]], 1);
}

__global__ __launch_bounds__(256) void scan_kernel(const int* __restrict__ cnt, int* __restrict__ rowptr,
                                                   int* __restrict__ cursor, int n) {
    __shared__ int part[256];
    int tid = threadIdx.x;
    int per = (n + 255) / 256;
    int start = tid * per;
    int end = start + per; if (end > n) end = n; if (start > n) start = n;
    int s = 0;
    for (int i = start; i < end; ++i) s += cnt[i];
    part[tid] = s;
    __syncthreads();
    for (int off = 1; off < 256; off <<= 1) {
        int v = (tid >= off) ? part[tid - off] : 0;
        __syncthreads();
        part[tid] += v;
        __syncthreads();
    }
    int base = (tid == 0) ? 0 : part[tid - 1];
    for (int i = start; i < end; ++i) {
        rowptr[i] = base; cursor[i] = base;
        base += cnt[i];
    }
    if (tid == 255) rowptr[n] = base;
}

__global__ __launch_bounds__(256) void scatter_kernel(const int* __restrict__ src, const int* __restrict__ dst,
                                                      const float* __restrict__ nrm, int* __restrict__ cursor,
                                                      int* __restrict__ esrc, float* __restrict__ ewt,
                                                      int* __restrict__ eid, int E) {
    int e = blockIdx.x * 256 + threadIdx.x;
    if (e >= E) return;
    int p = atomicAdd(&cursor[dst[e]], 1);
    esrc[p] = src[e]; ewt[p] = nrm[e]; eid[p] = e;
}

__global__ __launch_bounds__(256) void sortrows_kernel(const int* __restrict__ rowptr, int* __restrict__ esrc,
                                                       float* __restrict__ ewt, int* __restrict__ eid, int N) {
    int m = blockIdx.x * 256 + threadIdx.x;
    if (m >= N) return;
    int a = rowptr[m], b = rowptr[m + 1];
    for (int i = a + 1; i < b; ++i) {
        int ke = eid[i]; int ks = esrc[i]; float kw = ewt[i];
        int j = i - 1;
        while (j >= a && eid[j] > ke) { eid[j+1]=eid[j]; esrc[j+1]=esrc[j]; ewt[j+1]=ewt[j]; --j; }
        eid[j+1] = ke; esrc[j+1] = ks; ewt[j+1] = kw;
    }
}

// ======================= converts =======================
__global__ __launch_bounds__(256) void convert_flat(const float* __restrict__ in, unsigned short* __restrict__ out,
                                                    size_t n4) {
    for (size_t i = blockIdx.x * 256 + threadIdx.x; i < n4; i += (size_t)gridDim.x * 256) {
        float4 v = reinterpret_cast<const float4*>(in)[i];
        ushort4 o;
        o.x = f2bf(v.x); o.y = f2bf(v.y); o.z = f2bf(v.z); o.w = f2bf(v.w);
        reinterpret_cast<ushort4*>(out)[i] = o;
    }
}

// x fp32 [b*NN0+m][3] -> bf16 node-major [m][b*3+f] (96 cols), LDS transpose per 32-m tile
__global__ __launch_bounds__(256) void xcopy_T(const float* __restrict__ x, unsigned short* __restrict__ out) {
    __shared__ unsigned short sh[32 * 96];
    const int m0 = blockIdx.x * 32;
    const int tid = threadIdx.x;
    const int b = tid >> 3, mi = tid & 7;
#pragma unroll
    for (int ii = 0; ii < 4; ++ii) {
        int mm = mi + ii * 8;
        const float* p = x + ((size_t)b * NN0 + m0 + mm) * 3;
        sh[mm * 96 + b * 3 + 0] = f2bf(p[0]);
        sh[mm * 96 + b * 3 + 1] = f2bf(p[1]);
        sh[mm * 96 + b * 3 + 2] = f2bf(p[2]);
    }
    __syncthreads();
    unsigned int* dst = (unsigned int*)(out + (size_t)m0 * 96);
    const unsigned int* srcp = (const unsigned int*)sh;
    for (int i = tid; i < 32 * 48; i += 256) dst[i] = srcp[i];
}

// ======================= sparse props (bf16) =======================
__global__ __launch_bounds__(256) void sparse_prop16(const int* __restrict__ rowptr, const int* __restrict__ esrc,
                                                     const float* __restrict__ ewt,
                                                     const unsigned short* __restrict__ Tin,
                                                     const unsigned short* __restrict__ Tprev,
                                                     unsigned short* __restrict__ Tout, float s, float t) {
    int g = blockIdx.x * 256 + threadIdx.x;
    int m = g >> 6, lane = g & 63;
    int e0 = rowptr[m], e1 = rowptr[m + 1];
    float acc[8] = {};
    for (int e = e0; e < e1; ++e) {
        float w = ewt[e];
        short8v v = *reinterpret_cast<const short8v*>(Tin + (size_t)esrc[e] * 512 + lane * 8);
#pragma unroll
        for (int j = 0; j < 8; ++j) acc[j] += w * bf2f((unsigned short)v[j]);
    }
    float r[8];
    if (Tprev) {
        short8v pv = *reinterpret_cast<const short8v*>(Tprev + (size_t)m * 512 + lane * 8);
#pragma unroll
        for (int j = 0; j < 8; ++j) r[j] = s * acc[j] + t * bf2f((unsigned short)pv[j]);
    } else {
#pragma unroll
        for (int j = 0; j < 8; ++j) r[j] = s * acc[j];
    }
    uint4 ov;
    ov.x = pk2(r[0], r[1]); ov.y = pk2(r[2], r[3]); ov.z = pk2(r[4], r[5]); ov.w = pk2(r[6], r[7]);
    *reinterpret_cast<uint4*>(Tout + (size_t)m * 512 + lane * 8) = ov;
}

__global__ __launch_bounds__(256) void sparse_prop3(const int* __restrict__ rowptr, const int* __restrict__ esrc,
                                                    const float* __restrict__ ewt,
                                                    const unsigned short* __restrict__ Tin,
                                                    const unsigned short* __restrict__ Tprev,
                                                    unsigned short* __restrict__ Tout, float s, float t) {
    int g = blockIdx.x * 256 + threadIdx.x;
    int m = g / 96, c = g - m * 96;
    int e0 = rowptr[m], e1 = rowptr[m + 1];
    float acc = 0.f;
    for (int e = e0; e < e1; ++e)
        acc += ewt[e] * bf2f(Tin[(size_t)esrc[e] * 96 + c]);
    float v = s * acc;
    if (Tprev) v += t * bf2f(Tprev[(size_t)m * 96 + c]);
    Tout[(size_t)m * 96 + c] = f2bf(v);
}

// ======================= fused sparse epilogue -> bf16 node-major =======================
template <int FIN, int FOUT>
__global__ __launch_bounds__(256) void sparse_epi(const unsigned short* __restrict__ S, size_t slot,
                                                  const float* __restrict__ W, const float* __restrict__ bias,
                                                  unsigned short* __restrict__ out, int relu) {
    __shared__ float Ws[6 * FIN * FOUT];
    for (int i = threadIdx.x; i < 6 * FIN * FOUT; i += 256) Ws[i] = W[i];
    __syncthreads();
    int g = blockIdx.x * 256 + threadIdx.x;   // g = m*32 + b
    int m = g >> 5, b = g & 31;
    float oa[FOUT];
#pragma unroll
    for (int o = 0; o < FOUT; ++o) oa[o] = bias ? bias[o] : 0.f;
    for (int k = 0; k < 6; ++k) {
        const unsigned short* p = S + (size_t)k * slot + (size_t)m * (32 * FIN) + b * FIN;
        float xv[FIN];
        if constexpr (FIN == 16) {
            short8v v0 = *reinterpret_cast<const short8v*>(p);
            short8v v1 = *reinterpret_cast<const short8v*>(p + 8);
#pragma unroll
            for (int f = 0; f < 8; ++f) { xv[f] = bf2f((unsigned short)v0[f]); xv[f + 8] = bf2f((unsigned short)v1[f]); }
        } else {
#pragma unroll
            for (int f = 0; f < FIN; ++f) xv[f] = bf2f(p[f]);
        }
#pragma unroll
        for (int f = 0; f < FIN; ++f)
#pragma unroll
            for (int o = 0; o < FOUT; ++o) oa[o] += xv[f] * Ws[(k * FIN + f) * FOUT + o];
    }
    unsigned short* orow = out + (size_t)m * (32 * FOUT) + b * FOUT;
    unsigned int u[FOUT / 2];
#pragma unroll
    for (int o = 0; o < FOUT / 2; ++o) {
        float a = oa[2 * o], c = oa[2 * o + 1];
        if (relu) { a = fmaxf(a, 0.f); c = fmaxf(c, 0.f); }
        u[o] = pk2(a, c);
    }
#pragma unroll
    for (int q = 0; q < FOUT / 8; ++q)
        reinterpret_cast<uint4*>(orow)[q] = make_uint4(u[4 * q], u[4 * q + 1], u[4 * q + 2], u[4 * q + 3]);
}

// final epilogue: FIN=16 -> 3, fp32 d_out at (b*NN0+m)*3, LDS-staged contiguous writes
__global__ __launch_bounds__(256) void sparse_epi_final(const unsigned short* __restrict__ S, size_t slot,
                                                        const float* __restrict__ W, float* __restrict__ dout) {
    __shared__ float Ws[6 * 16 * 3];
    __shared__ float sh[32 * 24];
    for (int i = threadIdx.x; i < 288; i += 256) Ws[i] = W[i];
    __syncthreads();
    const int tid = threadIdx.x;
    const int mm = tid >> 5, b = tid & 31;
    const int m = blockIdx.x * 8 + mm;
    float o0 = 0.f, o1 = 0.f, o2 = 0.f;
    for (int k = 0; k < 6; ++k) {
        const unsigned short* p = S + (size_t)k * slot + (size_t)m * 512 + b * 16;
        short8v v0 = *reinterpret_cast<const short8v*>(p);
        short8v v1 = *reinterpret_cast<const short8v*>(p + 8);
#pragma unroll
        for (int f = 0; f < 16; ++f) {
            float xf = bf2f((unsigned short)(f < 8 ? v0[f] : v1[f - 8]));
            o0 += xf * Ws[(k * 16 + f) * 3 + 0];
            o1 += xf * Ws[(k * 16 + f) * 3 + 1];
            o2 += xf * Ws[(k * 16 + f) * 3 + 2];
        }
    }
    sh[b * 24 + mm * 3 + 0] = o0;
    sh[b * 24 + mm * 3 + 1] = o1;
    sh[b * 24 + mm * 3 + 2] = o2;
    __syncthreads();
    const size_t base = (size_t)blockIdx.x * 24;
    for (int i = tid; i < 768; i += 256) {
        int b2 = i / 24, r = i - b2 * 24;
        dout[(size_t)b2 * (NN0 * 3) + base + r] = sh[i];
    }
}

// ======================= pools =======================
__device__ __forceinline__ float ldv(const float* p) { return *p; }
__device__ __forceinline__ float ldv(const unsigned short* p) { return bf2f(*p); }

template <typename TI>
__global__ __launch_bounds__(256) void pool_cT(const TI* __restrict__ in, const int* __restrict__ idx,
                                               const float* __restrict__ w, unsigned short* __restrict__ out,
                                               int C, int Mnew) {
    __shared__ float tile[32][33];
    const int m0 = blockIdx.x * 32, c0 = blockIdx.y * 32;
    const int tx = threadIdx.x & 31, ty = threadIdx.x >> 5;
#pragma unroll
    for (int i = 0; i < 4; ++i) {
        int mn = m0 + ty + i * 8;
        const int* ir = idx + mn * 3; const float* wr = w + mn * 3;
        float v = wr[0] * ldv(in + (size_t)ir[0] * C + c0 + tx)
                + wr[1] * ldv(in + (size_t)ir[1] * C + c0 + tx)
                + wr[2] * ldv(in + (size_t)ir[2] * C + c0 + tx);
        tile[ty + i * 8][tx] = v;
    }
    __syncthreads();
#pragma unroll
    for (int i = 0; i < 4; ++i) {
        int c = c0 + ty + i * 8;
        out[(size_t)c * Mnew + m0 + tx] = f2bf(tile[tx][ty + i * 8]);
    }
}

__global__ __launch_bounds__(256) void pool_row16(const unsigned short* __restrict__ in, const int* __restrict__ idx,
                                                  const float* __restrict__ w, unsigned short* __restrict__ out) {
    int g = blockIdx.x * 256 + threadIdx.x;
    int m = g >> 6, lane = g & 63;
    const int* ir = idx + m * 3; const float* wr = w + m * 3;
    short8v a = *reinterpret_cast<const short8v*>(in + (size_t)ir[0] * 512 + lane * 8);
    short8v b = *reinterpret_cast<const short8v*>(in + (size_t)ir[1] * 512 + lane * 8);
    short8v c = *reinterpret_cast<const short8v*>(in + (size_t)ir[2] * 512 + lane * 8);
    float r[8];
#pragma unroll
    for (int j = 0; j < 8; ++j)
        r[j] = wr[0] * bf2f((unsigned short)a[j]) + wr[1] * bf2f((unsigned short)b[j]) + wr[2] * bf2f((unsigned short)c[j]);
    uint4 ov;
    ov.x = pk2(r[0], r[1]); ov.y = pk2(r[2], r[3]); ov.z = pk2(r[4], r[5]); ov.w = pk2(r[6], r[7]);
    *reinterpret_cast<uint4*>(out + (size_t)m * 512 + lane * 8) = ov;
}

__global__ __launch_bounds__(256) void pool_f32(const unsigned short* __restrict__ in, const int* __restrict__ idx,
                                                const float* __restrict__ w, float* __restrict__ out) {
    int g = blockIdx.x * 256 + threadIdx.x;   // 80*1024
    int m = g >> 10, c = g & 1023;
    const int* ir = idx + m * 3; const float* wr = w + m * 3;
    out[g] = wr[0] * bf2f(in[(size_t)ir[0] * 1024 + c])
           + wr[1] * bf2f(in[(size_t)ir[1] * 1024 + c])
           + wr[2] * bf2f(in[(size_t)ir[2] * 1024 + c]);
}

// ======================= MFMA prop GEMM, 2-phase double-buffered ==========================
// SPLIT: grid.z = K-chunk idx; writes fp32 partial Pf[z][C][M]. else: full epilogue to Ob.
template <int MF, bool SPLIT>
__global__ __launch_bounds__(256) void gemm_mfma(const unsigned short* __restrict__ Ab,
                                                 const unsigned short* __restrict__ Xb,
                                                 const unsigned short* __restrict__ Pb,
                                                 unsigned short* __restrict__ Ob,
                                                 float* __restrict__ Pf,
                                                 int Mn, int KC, float s, float t) {
    constexpr int BM = MF * 64;
    constexpr int ABYTES = BM * 64 * 2;          // one A buffer
    constexpr int XBYTES = 64 * 64 * 2;
    constexpr int SEGA = ABYTES / 1024 / 4;      // A 1KB-segments per wave
    __shared__ unsigned short As[2][BM * 64];
    __shared__ unsigned short Xs[2][64 * 64];
    const int tid = threadIdx.x;
    const int lane = tid & 63, wid = tid >> 6;
    // XCD-chunked swizzle over x-y (nwg % 8 == 0 for all our grids)
    int lin = blockIdx.y * gridDim.x + blockIdx.x;
    int nwg = gridDim.x * gridDim.y;
    int lin2 = (lin & 7) * (nwg >> 3) + (lin >> 3);
    int by = lin2 / gridDim.x, bx = lin2 - by * gridDim.x;
    const int bm = by * BM, bc = bx * 64;
    const int kbase = SPLIT ? blockIdx.z * KC : 0;
    const int NT = KC / 64;

    // precompute per-lane staging sources (advance by 64 shorts per K-step) + wave-uniform LDS offsets
    const unsigned short* gAsrc[SEGA];
    unsigned int ldsAoff[SEGA];
#pragma unroll
    for (int i = 0; i < SEGA; ++i) {
        int o = (wid * SEGA + i) * 1024 + lane * 16;
        int row = o >> 7;
        int colb = (o & 127) ^ ((row & 7) << 4);
        gAsrc[i] = Ab + (size_t)(bm + row) * Mn + kbase + (colb >> 1);
        ldsAoff[i] = (unsigned int)(wid * SEGA + i) * 1024;
    }
    const unsigned short* gXsrc[2];
    unsigned int ldsXoff[2];
#pragma unroll
    for (int i = 0; i < 2; ++i) {
        int o = (wid * 2 + i) * 1024 + lane * 16;
        int row = o >> 7;
        int colb = (o & 127) ^ ((row & 7) << 4);
        gXsrc[i] = Xb + (size_t)(bc + row) * Mn + kbase + (colb >> 1);
        ldsXoff[i] = (unsigned int)(wid * 2 + i) * 1024;
    }

    auto STAGE = [&](int buf, int ko) {
#pragma unroll
        for (int i = 0; i < SEGA; ++i)
            __builtin_amdgcn_global_load_lds((const __attribute__((address_space(1))) void*)(gAsrc[i] + ko),
                                             (__attribute__((address_space(3))) void*)((char*)As + buf * ABYTES + ldsAoff[i]),
                                             16, 0, 0);
#pragma unroll
        for (int i = 0; i < 2; ++i)
            __builtin_amdgcn_global_load_lds((const __attribute__((address_space(1))) void*)(gXsrc[i] + ko),
                                             (__attribute__((address_space(3))) void*)((char*)Xs + buf * XBYTES + ldsXoff[i]),
                                             16, 0, 0);
    };

    f32x4 acc[MF][4] = {};

    STAGE(0, 0);
    __syncthreads();   // drain prologue loads
    for (int tt = 0; tt < NT; ++tt) {
        const int cur = tt & 1;
        if (tt + 1 < NT) STAGE(cur ^ 1, (tt + 1) * 64);   // issue next tile; lands under this tile's MFMA
        const char* Ac = (const char*)As + cur * ABYTES;
        const char* Xc = (const char*)Xs + cur * XBYTES;
#pragma unroll
        for (int kk = 0; kk < 2; ++kk) {
            short8v a[MF], b[4];
#pragma unroll
            for (int mf = 0; mf < MF; ++mf) {
                int r = wid * (MF * 16) + mf * 16 + (lane & 15);
                int cb = kk * 64 + ((lane >> 4) * 16);
                int addr = r * 128 + (cb ^ ((r & 7) << 4));
                a[mf] = *reinterpret_cast<const short8v*>(Ac + addr);
            }
#pragma unroll
            for (int cf = 0; cf < 4; ++cf) {
                int r = cf * 16 + (lane & 15);
                int cb = kk * 64 + ((lane >> 4) * 16);
                int addr = r * 128 + (cb ^ ((r & 7) << 4));
                b[cf] = *reinterpret_cast<const short8v*>(Xc + addr);
            }
#pragma unroll
            for (int mf = 0; mf < MF; ++mf)
#pragma unroll
                for (int cf = 0; cf < 4; ++cf)
                    acc[mf][cf] = __builtin_amdgcn_mfma_f32_16x16x32_bf16(a[mf], b[cf], acc[mf][cf], 0, 0, 0);
        }
        __syncthreads();   // drains next-tile loads (covered by MFMA above) + syncs buffers
    }

#pragma unroll
    for (int mf = 0; mf < MF; ++mf) {
        int m0 = bm + wid * (MF * 16) + mf * 16 + ((lane >> 4) * 4);
#pragma unroll
        for (int cf = 0; cf < 4; ++cf) {
            int c = bc + cf * 16 + (lane & 15);
            size_t base = (size_t)c * Mn + m0;
            if constexpr (SPLIT) {
                size_t zbase = (size_t)blockIdx.z * (size_t)(gridDim.x * 64) * (size_t)Mn;
                *reinterpret_cast<float4*>(Pf + zbase + base) =
                    make_float4(acc[mf][cf][0], acc[mf][cf][1], acc[mf][cf][2], acc[mf][cf][3]);
            } else {
                float v0 = s * acc[mf][cf][0], v1 = s * acc[mf][cf][1];
                float v2 = s * acc[mf][cf][2], v3 = s * acc[mf][cf][3];
                if (Pb) {
                    uint2 pv = *reinterpret_cast<const uint2*>(Pb + base);
                    v0 += t * bf2f((unsigned short)(pv.x & 0xffff));
                    v1 += t * bf2f((unsigned short)(pv.x >> 16));
                    v2 += t * bf2f((unsigned short)(pv.y & 0xffff));
                    v3 += t * bf2f((unsigned short)(pv.y >> 16));
                }
                uint2 ov;
                ov.x = pk2(v0, v1); ov.y = pk2(v2, v3);
                *reinterpret_cast<uint2*>(Ob + base) = ov;
            }
        }
    }
}

// split-K reduce: Out[g] = bf16( s*sum_ks Pf[ks][g] + t*Prev[g] ), 4 elems/thread
__global__ __launch_bounds__(256) void sk_reduce(const float* __restrict__ Pf,
                                                 const unsigned short* __restrict__ Prev,
                                                 unsigned short* __restrict__ Out,
                                                 int n4, int KS, float s, float t) {
    int g = blockIdx.x * 256 + threadIdx.x;
    if (g >= n4) return;
    float4 a = reinterpret_cast<const float4*>(Pf)[g];
    for (int ks = 1; ks < KS; ++ks) {
        float4 b = reinterpret_cast<const float4*>(Pf)[(size_t)ks * n4 + g];
        a.x += b.x; a.y += b.y; a.z += b.z; a.w += b.w;
    }
    float v0 = s * a.x, v1 = s * a.y, v2 = s * a.z, v3 = s * a.w;
    if (Prev) {
        uint2 pv = reinterpret_cast<const uint2*>(Prev)[g];
        v0 += t * bf2f((unsigned short)(pv.x & 0xffff));
        v1 += t * bf2f((unsigned short)(pv.x >> 16));
        v2 += t * bf2f((unsigned short)(pv.y & 0xffff));
        v3 += t * bf2f((unsigned short)(pv.y >> 16));
    }
    uint2 ov;
    ov.x = pk2(v0, v1); ov.y = pk2(v2, v3);
    reinterpret_cast<uint2*>(Out)[g] = ov;
}

// ======================= dense fused epilogue -> bf16 [m][32*FOUT] =======================
template <int FIN, int FOUT>
__global__ __launch_bounds__(256) void epi_layer(const unsigned short* __restrict__ Tb, size_t tslot,
                                                 const float* __restrict__ W, const float* __restrict__ bias,
                                                 unsigned short* __restrict__ out, int M) {
    __shared__ float Ws[6 * FIN * FOUT];
    for (int i = threadIdx.x; i < 6 * FIN * FOUT; i += 256) Ws[i] = W[i];
    __syncthreads();
    int g = blockIdx.x * 256 + threadIdx.x;   // g = b*M + m
    int b = g / M, m = g - b * M;
    float oa[FOUT];
#pragma unroll
    for (int o = 0; o < FOUT; ++o) oa[o] = bias[o];
    for (int k = 0; k < 6; ++k) {
        const unsigned short* Tk = Tb + (size_t)k * tslot + (size_t)b * FIN * M + m;
#pragma unroll
        for (int f = 0; f < FIN; ++f) {
            float xf = bf2f(Tk[(size_t)f * M]);
#pragma unroll
            for (int o = 0; o < FOUT; ++o) oa[o] += xf * Ws[(k * FIN + f) * FOUT + o];
        }
    }
    unsigned short* orow = out + (size_t)m * (32 * FOUT) + b * FOUT;
    unsigned int u[FOUT / 2];
#pragma unroll
    for (int o = 0; o < FOUT / 2; ++o)
        u[o] = pk2(fmaxf(oa[2 * o], 0.f), fmaxf(oa[2 * o + 1], 0.f));
#pragma unroll
    for (int q = 0; q < FOUT / 8; ++q)
        reinterpret_cast<uint4*>(orow)[q] = make_uint4(u[4 * q], u[4 * q + 1], u[4 * q + 2], u[4 * q + 3]);
}

// ======================= FCs =======================
__global__ __launch_bounds__(256) void fc_enc_kernel(const float* __restrict__ h, const float* __restrict__ w,
                                                     const float* __restrict__ bias, float* __restrict__ z) {
    __shared__ float sh[256];
    int b = blockIdx.x, o = threadIdx.x & 63, q = threadIdx.x >> 6;
    float acc = 0.f;
    for (int n = q * 20; n < q * 20 + 20; ++n)
#pragma unroll
        for (int f = 0; f < 32; ++f)
            acc += h[((size_t)n * 32 + b) * 32 + f] * w[(size_t)o * 2560 + n * 32 + f];
    sh[threadIdx.x] = acc;
    __syncthreads();
    if (q == 0) z[b * 64 + o] = fmaxf(sh[o] + sh[64 + o] + sh[128 + o] + sh[192 + o] + bias[o], 0.f);
}

__global__ __launch_bounds__(256) void fc_dec_kernel(const float* __restrict__ z, const float* __restrict__ w,
                                                     const float* __restrict__ bias, float* __restrict__ out) {
    int g = blockIdx.x * 256 + threadIdx.x;   // 80*32*32, layout [n][b*32+f]
    if (g >= 80 * 32 * 32) return;
    int f = g % 32; int b = (g / 32) % 32; int n = g / 1024;
    int j = n * 32 + f;
    float acc = bias[j];
    const float* wr = w + (size_t)j * 64;
    const float* zr = z + b * 64;
#pragma unroll
    for (int o = 0; o < 64; ++o) acc += zr[o] * wr[o];
    out[g] = fmaxf(acc, 0.f);
}

// ======================= host orchestration =======================
extern "C" void kernel_launch(void* const* d_in, const int* in_sizes, int n_in,
                              void* d_out, int out_size, void* d_ws, size_t ws_size,
                              hipStream_t stream) {
    (void)n_in; (void)out_size; (void)ws_size;
    const float* x     = (const float*)d_in[0];
    const int*   ei    = (const int*)d_in[1];
    const float* anorm = (const float*)d_in[2];
    const float* adjs[3] = { (const float*)d_in[4], (const float*)d_in[5], (const float*)d_in[6] };
    const int*   dn_idx[4] = { (const int*)d_in[7],  (const int*)d_in[11], (const int*)d_in[15], (const int*)d_in[19] };
    const float* dn_w[4]   = { (const float*)d_in[8],(const float*)d_in[12],(const float*)d_in[16],(const float*)d_in[20] };
    const int*   up_idx[4] = { (const int*)d_in[9],  (const int*)d_in[13], (const int*)d_in[17], (const int*)d_in[21] };
    const float* up_w[4]   = { (const float*)d_in[10],(const float*)d_in[14],(const float*)d_in[18],(const float*)d_in[22] };
    const float* W_enc[4] = { (const float*)d_in[23], (const float*)d_in[25], (const float*)d_in[27], (const float*)d_in[29] };
    const float* b_enc[4] = { (const float*)d_in[24], (const float*)d_in[26], (const float*)d_in[28], (const float*)d_in[30] };
    const float* W_dec[5] = { (const float*)d_in[31], (const float*)d_in[33], (const float*)d_in[35], (const float*)d_in[37], (const float*)d_in[39] };
    const float* b_dec[4] = { (const float*)d_in[32], (const float*)d_in[34], (const float*)d_in[36], (const float*)d_in[38] };
    const float* enc_w = (const float*)d_in[40];
    const float* enc_b = (const float*)d_in[41];
    const float* dec_w = (const float*)d_in[42];
    const float* dec_b = (const float*)d_in[43];
    const int E = in_sizes[2];

    // ---- workspace layout (live-range aliased) ----
    const size_t SLOT16 = (size_t)NN0 * 512;          // ushort elems, 21 MB
    const size_t SLOT3  = (size_t)NN0 * 96;
    unsigned short* S = (unsigned short*)d_ws;        // sparse slots; also split-K partial region (disjoint in time)
    float* Pf = (float*)d_ws;                         // fp32 partials during dense layers (<= 42 MB < 3*SLOT16)
    unsigned short* Tb = S + 3 * SLOT16;
    unsigned short* HB = Tb + (size_t)6 * 512 * 5120;
    char* p = (char*)(HB + SLOT16);
    unsigned short* adj1b = (unsigned short*)p; p += (size_t)5120 * 5120 * 2;
    unsigned short* adj2b = (unsigned short*)p; p += (size_t)1280 * 1280 * 2;
    unsigned short* adj3b = (unsigned short*)p; p += (size_t)320 * 320 * 2;
    int* rowptr = (int*)p;  p += (NN0 + 4) * sizeof(int);
    int* cnt    = (int*)p;  p += NN0 * sizeof(int);
    int* cursor = (int*)p;  p += NN0 * sizeof(int);
    int* esrc   = (int*)p;  p += (size_t)E * sizeof(int);
    int* eid    = (int*)p;  p += (size_t)E * sizeof(int);
    float* ewt  = (float*)p; p += (size_t)E * sizeof(float);
    float* lat0 = (float*)p; p += 80 * 1024 * sizeof(float);
    float* zb   = (float*)p; p += 32 * 64 * sizeof(float);
    float* lat1 = (float*)p;

    // ---- CSR build (deterministic via per-row sort by edge id) ----
    hipMemsetAsync(cnt, 0, NN0 * sizeof(int), stream);
    count_kernel<<<(E + 255) / 256, 256, 0, stream>>>(ei + E, cnt, E);
    scan_kernel<<<1, 256, 0, stream>>>(cnt, rowptr, cursor, NN0);
    scatter_kernel<<<(E + 255) / 256, 256, 0, stream>>>(ei, ei + E, anorm, cursor, esrc, ewt, eid, E);
    sortrows_kernel<<<(NN0 + 255) / 256, 256, 0, stream>>>(rowptr, esrc, ewt, eid, NN0);

    // ---- adjacency bf16 conversion ----
    convert_flat<<<2048, 256, 0, stream>>>(adjs[0], adj1b, (size_t)5120 * 5120 / 4);
    convert_flat<<<512, 256, 0, stream>>>(adjs[1], adj2b, (size_t)1280 * 1280 / 4);
    convert_flat<<<64, 256, 0, stream>>>(adjs[2], adj3b, (size_t)320 * 320 / 4);

    // ---- helpers ----
    auto dense_layer = [&](const unsigned short* Ab, int M, int FIN, int FOUT,
                           const float* W, const float* bias, unsigned short* HBout) {
        const int C = 32 * FIN;
        const size_t tslot = (size_t)C * M;
        const int CM4 = (int)(tslot / 4);
        int KS, KC, BMv, MFv;
        if (M == 5120)      { BMv = 128; MFv = 2; KS = 2; KC = 2560; }
        else if (M == 1280) { BMv = 64;  MFv = 1; KS = 4; KC = 320;  }
        else                { BMv = 64;  MFv = 1; KS = 1; KC = M;    }
        dim3 gg(C / 64, M / BMv, KS);
        for (int k = 1; k < 6; ++k) {
            const unsigned short* Xin = Tb + (size_t)(k - 1) * tslot;
            const unsigned short* Pv  = (k >= 2) ? Tb + (size_t)(k - 2) * tslot : nullptr;
            unsigned short* Oo = Tb + (size_t)k * tslot;
            float s = (k == 1) ? 1.f : 2.f;
            float t = (k == 1) ? 0.f : -1.f;
            if (KS > 1) {
                if (MFv == 2) gemm_mfma<2, true><<<gg, 256, 0, stream>>>(Ab, Xin, nullptr, nullptr, Pf, M, KC, s, t);
                else          gemm_mfma<1, true><<<gg, 256, 0, stream>>>(Ab, Xin, nullptr, nullptr, Pf, M, KC, s, t);
                sk_reduce<<<(CM4 + 255) / 256, 256, 0, stream>>>(Pf, Pv, Oo, CM4, KS, s, t);
            } else {
                gemm_mfma<1, false><<<gg, 256, 0, stream>>>(Ab, Xin, Pv, Oo, nullptr, M, KC, s, t);
            }
        }
        int blocks = M * 32 / 256;
        if (FIN == 16 && FOUT == 16)      epi_layer<16, 16><<<blocks, 256, 0, stream>>>(Tb, tslot, W, bias, HBout, M);
        else if (FIN == 16 && FOUT == 32) epi_layer<16, 32><<<blocks, 256, 0, stream>>>(Tb, tslot, W, bias, HBout, M);
        else                              epi_layer<32, 16><<<blocks, 256, 0, stream>>>(Tb, tslot, W, bias, HBout, M);
    };
    auto sparse_layer16 = [&](const float* W, const float* bias, int final_relu, unsigned short* out16) {
        for (int k = 1; k < 6; ++k) {
            const unsigned short* Tin = S + (size_t)(k - 1) * SLOT16;
            const unsigned short* Pv  = (k >= 2) ? S + (size_t)(k - 2) * SLOT16 : nullptr;
            sparse_prop16<<<NN0 / 4, 256, 0, stream>>>(rowptr, esrc, ewt, Tin, Pv, S + (size_t)k * SLOT16,
                                                       (k == 1) ? 1.f : 2.f, (k == 1) ? 0.f : -1.f);
        }
        if (out16) sparse_epi<16, 16><<<NN0 * 32 / 256, 256, 0, stream>>>(S, SLOT16, W, bias, out16, final_relu);
        else       sparse_epi_final<<<NN0 / 8, 256, 0, stream>>>(S, SLOT16, W, (float*)d_out);
    };

    // ======================= network =======================
    // --- encoder sparse layer (FIN=3) ---
    xcopy_T<<<NN0 / 32, 256, 0, stream>>>(x, S);
    for (int k = 1; k < 6; ++k) {
        const unsigned short* Tin = S + (size_t)(k - 1) * SLOT3;
        const unsigned short* Pv  = (k >= 2) ? S + (size_t)(k - 2) * SLOT3 : nullptr;
        sparse_prop3<<<NN0 * 96 / 256, 256, 0, stream>>>(rowptr, esrc, ewt, Tin, Pv, S + (size_t)k * SLOT3,
                                                         (k == 1) ? 1.f : 2.f, (k == 1) ? 0.f : -1.f);
    }
    sparse_epi<3, 16><<<NN0 * 32 / 256, 256, 0, stream>>>(S, SLOT3, W_enc[0], b_enc[0], HB, 1);
    // --- dense encoder ---
    { dim3 g(5120 / 32, 512 / 32);  pool_cT<unsigned short><<<g, 256, 0, stream>>>(HB, dn_idx[0], dn_w[0], Tb, 512, 5120); }
    dense_layer(adj1b, 5120, 16, 16, W_enc[1], b_enc[1], HB);
    { dim3 g(1280 / 32, 512 / 32);  pool_cT<unsigned short><<<g, 256, 0, stream>>>(HB, dn_idx[1], dn_w[1], Tb, 512, 1280); }
    dense_layer(adj2b, 1280, 16, 16, W_enc[2], b_enc[2], HB);
    { dim3 g(320 / 32, 512 / 32);   pool_cT<unsigned short><<<g, 256, 0, stream>>>(HB, dn_idx[2], dn_w[2], Tb, 512, 320); }
    dense_layer(adj3b, 320, 16, 32, W_enc[3], b_enc[3], HB);
    pool_f32<<<80 * 1024 / 256, 256, 0, stream>>>(HB, dn_idx[3], dn_w[3], lat0);
    fc_enc_kernel<<<32, 256, 0, stream>>>(lat0, enc_w, enc_b, zb);
    // --- decoder ---
    fc_dec_kernel<<<80 * 32 * 32 / 256, 256, 0, stream>>>(zb, dec_w, dec_b, lat1);
    { dim3 g(320 / 32, 1024 / 32);  pool_cT<float><<<g, 256, 0, stream>>>(lat1, up_idx[3], up_w[3], Tb, 1024, 320); }
    dense_layer(adj3b, 320, 32, 16, W_dec[0], b_dec[0], HB);
    { dim3 g(1280 / 32, 512 / 32);  pool_cT<unsigned short><<<g, 256, 0, stream>>>(HB, up_idx[2], up_w[2], Tb, 512, 1280); }
    dense_layer(adj2b, 1280, 16, 16, W_dec[1], b_dec[1], HB);
    { dim3 g(5120 / 32, 512 / 32);  pool_cT<unsigned short><<<g, 256, 0, stream>>>(HB, up_idx[1], up_w[1], Tb, 512, 5120); }
    dense_layer(adj1b, 5120, 16, 16, W_dec[2], b_dec[2], HB);
    pool_row16<<<NN0 / 4, 256, 0, stream>>>(HB, up_idx[0], up_w[0], S);   // -> S slot0
    // --- decoder sparse layers (FIN=16) ---
    sparse_layer16(W_dec[3], b_dec[3], 1, S);          // epi writes slot0 in-place (owner-thread-safe)
    sparse_layer16(W_dec[4], nullptr, 0, nullptr);     // final -> d_out
}